// Round 1
// 644.071 us; speedup vs baseline: 1.2023x; 1.2023x over previous
//
#include <hip/hip_runtime.h>
#include <math.h>

// ---------------------------------------------------------------------------
// CapsuleNet forward. R20: conv1 rewritten as bf16 MFMA implicit GEMM
// (im2col to padded global buffer + one-shot 64x256 MFMA blocks). The old
// fp32 direct conv was I-cache/latency-bound at 189us (VALUBusy 32%, occ 12%),
// 7x above its VALU floor. New path: wb1_k (weight frags) + im2col_k (21 MB
// bf16 patches, rows padded to 104 elems = 16B-aligned) + conv1_mfma_k
// (no LDS, no syncs, A/B frags straight from L2, fp32 accum, bias+relu+f2bf
// epilogue writing the same NHWC g_x1b layout pc_mfma_k consumes).
// Everything downstream of g_x1b is byte-identical to R19.
// ---------------------------------------------------------------------------

typedef unsigned short u16;
typedef short bf16x8 __attribute__((ext_vector_type(8)));
typedef float f32x4 __attribute__((ext_vector_type(4)));

#define PS 2359296   // 9216*256, one y2 partial buffer
#define KSPLIT 9
#define KSLICE 2304  // 20736/9
#define NSTAGE 36    // 2304/64

__device__ u16 g_x1b[256 * 400 * 256];          // conv1 out NHWC bf16 (52 MB)
__device__ u16 g_wbF[648 * 16 * 512];           // pc_w bf16, MFMA frag order (10.6 MB)
__device__ u16 g_y2p[(size_t)KSPLIT * PS];      // pc GEMM K-partials bf16 (42.5 MB)
__device__ float g_u[256 * 1152 * 8];           // squashed primary caps
__device__ u16 g_WU[(size_t)256 * 1152 * 160];  // u_hat bf16 (94.4 MB)
__device__ float g_ssum[3 * 256 * 160];
__device__ float g_v[3 * 256 * 160];
__device__ float g_h1[256 * 512];
__device__ float g_h2[256 * 1024];

// conv1-as-GEMM buffers
__device__ __attribute__((aligned(256))) u16 g_im2[(size_t)102400 * 104];  // im2col bf16, 104-padded rows (21.3 MB)
__device__ __attribute__((aligned(256))) u16 g_wb1[48 * 512];              // conv1_w frags: (kc*16+n16)*512 + l*8+j (48 KB)

__device__ __forceinline__ u16 f2bf(float f) {
  union { float f; unsigned u; } v; v.f = f;
  unsigned r = (v.u + 0x7FFFu + ((v.u >> 16) & 1u)) >> 16;  // RNE
  return (u16)r;
}
__device__ __forceinline__ float bf2f(u16 h) {
  union { unsigned u; float f; } v; v.u = ((unsigned)h) << 16;
  return v.f;
}

// ---------------- zero the atomic accumulators ----------------
__global__ __launch_bounds__(256) void zero_ssum_k() {
  int i = blockIdx.x * 256 + threadIdx.x;
  if (i < 3 * 256 * 160) g_ssum[i] = 0.f;
}

// ------ pc_w fp32 [oc][ic][kp] -> bf16 fragment order --------------------
__global__ __launch_bounds__(256) void wconv_k(const float* __restrict__ w) {
  __shared__ float Ws[256 * 16];   // [ic][ocl] 16 KB
  int n16 = blockIdx.x;   // 0..15
  int kp = blockIdx.y;    // 0..80
  int t = threadIdx.x;
  for (int idx = t; idx < 4096; idx += 256) {
    int ic = idx >> 4;
    int ocl = idx & 15;
    Ws[idx] = w[(size_t)(n16 * 16 + ocl) * 20736 + ic * 81 + kp];
  }
  __syncthreads();
  for (int idx = t; idx < 4096; idx += 256) {
    int c = idx >> 9;          // k-chunk within this kp: 0..7
    int r = idx & 511;
    int ll = r >> 3, j = r & 7;
    int ic = c * 32 + ((ll >> 4) << 3) + j;
    g_wbF[(((size_t)kp * 8 + c) * 16 + n16) * 512 + r] = f2bf(Ws[ic * 16 + (ll & 15)]);
  }
}

// ------ conv1_w fp32 [oc][81] -> bf16 MFMA B-fragment order ----------------
// frag (kc,n16): elem (ll*8+j) = w[oc = n16*16 + (ll&15)][k = kc*32 + (ll>>4)*8 + j]
// k >= 81 zero-padded.
__global__ __launch_bounds__(256) void wb1_k(const float* __restrict__ w) {
  int idx = blockIdx.x * 256 + threadIdx.x;   // 0..24575
  int frag = idx >> 9;     // kc*16 + n16
  int r = idx & 511;
  int ll = r >> 3, j = r & 7;
  int kc = frag >> 4, n16 = frag & 15;
  int k = kc * 32 + ((ll >> 4) << 3) + j;
  int oc = n16 * 16 + (ll & 15);
  float v = (k < 81) ? w[oc * 81 + k] : 0.f;
  g_wb1[idx] = f2bf(v);
}

// ------ im2col: input fp32 [b][28][28] -> bf16 patches [m][104] ------------
// row m = b*400 + oy*20 + ox; elem k = ky*9+kx -> in[b][oy+ky][ox+kx];
// k in [81,104) zeroed (pad so MFMA sees 0, no garbage NaN/Inf).
__global__ __launch_bounds__(256) void im2col_k(const float* __restrict__ in) {
  __shared__ u16 im_s[784];
  int b = blockIdx.x;
  int t = threadIdx.x;
  for (int i = t; i < 784; i += 256) im_s[i] = f2bf(in[b * 784 + i]);
  __syncthreads();
  u16* outp = g_im2 + (size_t)b * 41600;   // 400*104
  int base = blockIdx.y * 2600;            // octet halves (5200 octets/image)
  for (int ii = t; ii < 2600; ii += 256) {
    int idx = base + ii;
    int p = idx / 13;                      // pixel 0..399
    int ko = (idx - p * 13) * 8;           // 0,8,...,96
    int oy = p / 20, ox = p - oy * 20;
    bf16x8 v;
#pragma unroll
    for (int e = 0; e < 8; e++) {
      int k = ko + e;
      u16 x = 0;
      if (k < 81) {
        int ky = k / 9, kx = k - ky * 9;
        x = im_s[(oy + ky) * 28 + ox + kx];
      }
      v[e] = (short)x;
    }
    *(bf16x8*)(outp + (size_t)p * 104 + ko) = v;   // 16B aligned (208B rows)
  }
}

// ------ conv1 as MFMA GEMM: M=102400, N=256, K=96 --------------------------
// One-shot blocks: 64 rows x 256 cols, 4 waves (wave = oc-quarter), no LDS.
// A frags direct from g_im2 (L2), B frags from g_wb1. Epilogue: +bias, relu,
// f2bf -> g_x1b NHWC (identical layout to old conv1_relu_k output).
__global__ __launch_bounds__(256) void conv1_mfma_k(const float* __restrict__ bias) {
  int t = threadIdx.x;
  int wq = t >> 6;          // wave's oc-quarter
  int l = t & 63;
  int q = l >> 4, c15 = l & 15;
  int m0 = blockIdx.x * 64;

  // B fragments: 3 kc x 4 n16 (this wave's quarter)
  bf16x8 bf[3][4];
#pragma unroll
  for (int kc = 0; kc < 3; kc++)
#pragma unroll
    for (int jn = 0; jn < 4; jn++)
      bf[kc][jn] = *(const bf16x8*)&g_wb1[((kc * 16 + wq * 4 + jn) << 9) + l * 8];

  // A fragments: 4 m-tiles x 3 kc
  bf16x8 af[4][3];
#pragma unroll
  for (int mt = 0; mt < 4; mt++) {
    const u16* ap = g_im2 + (size_t)(m0 + mt * 16 + c15) * 104 + q * 8;
#pragma unroll
    for (int kc = 0; kc < 3; kc++)
      af[mt][kc] = *(const bf16x8*)(ap + kc * 32);
  }

  f32x4 acc[4][4];
#pragma unroll
  for (int mt = 0; mt < 4; mt++)
#pragma unroll
    for (int jn = 0; jn < 4; jn++) acc[mt][jn] = (f32x4){0.f, 0.f, 0.f, 0.f};

#pragma unroll
  for (int kc = 0; kc < 3; kc++)
#pragma unroll
    for (int mt = 0; mt < 4; mt++)
#pragma unroll
      for (int jn = 0; jn < 4; jn++)
        acc[mt][jn] = __builtin_amdgcn_mfma_f32_16x16x32_bf16(af[mt][kc], bf[kc][jn], acc[mt][jn], 0, 0, 0);

  float bv[4];
#pragma unroll
  for (int jn = 0; jn < 4; jn++) bv[jn] = bias[wq * 64 + jn * 16 + c15];

#pragma unroll
  for (int mt = 0; mt < 4; mt++) {
#pragma unroll
    for (int rg = 0; rg < 4; rg++) {
      int row = m0 + mt * 16 + q * 4 + rg;
      int b = row / 400;
      int p = row - b * 400;
      u16* ob = g_x1b + (size_t)b * 102400 + p * 256;
#pragma unroll
      for (int jn = 0; jn < 4; jn++) {
        int col = wq * 64 + jn * 16 + c15;
        ob[col] = f2bf(fmaxf(acc[mt][jn][rg] + bv[jn], 0.f));
      }
    }
  }
}

// ---------------- pc conv: bf16 MFMA GEMM, GLD-staged A (xor swizzle) ------
__global__ __launch_bounds__(256) void pc_mfma_k() {
  __shared__ u16 As[64 * 64];  // unpadded; chunk index xor-swizzled by row&7
  int t = threadIdx.x;
  int m0 = blockIdx.x * 64;
  int ks0 = blockIdx.y * KSLICE;
  u16* outp = g_y2p + (size_t)blockIdx.y * PS;

  int w = t >> 6, l = t & 63, quad = l >> 4, c15 = l & 15;
  int wm = w & 1, wn = w >> 1;

  // A staging: thread t fills physical chunk (t&7) of rows sr and sr+32;
  // content = logical chunk (t&7)^(sr&7) (source-side xor swizzle).
  int sr = t >> 3;
  int sc = t & 7;
  int cch = sc ^ (sr & 7);
  int fixed0, fixed1;
  {
    int m = m0 + sr;
    int bb = m / 36;
    int s = m - bb * 36;
    int oy = s / 6;
    int ox = s - oy * 6;
    fixed0 = bb * 102400 + oy * 10240 + ox * 512 + cch * 8;
    m += 32;
    bb = m / 36;
    s = m - bb * 36;
    oy = s / 6;
    ox = s - oy * 6;
    fixed1 = bb * 102400 + oy * 10240 + ox * 512 + cch * 8;
  }
  // wave-uniform LDS bases: wave w covers bytes w*1024 (+4096 for upper rows)
  u16* lds0 = &As[(t >> 6) * 512];
  u16* lds1 = &As[2048 + (t >> 6) * 512];

  // B fragment offsets in elements (g_wbF spans 10.6MB -> 32-bit safe)
  int bofs[8];
#pragma unroll
  for (int g = 0; g < 2; g++)
#pragma unroll
    for (int jn = 0; jn < 4; jn++)
      bofs[g * 4 + jn] = ((g * 8 + wn * 4 + jn) << 9) + l * 8;

  f32x4 acc[2][8];
#pragma unroll
  for (int i = 0; i < 2; i++)
#pragma unroll
    for (int j = 0; j < 8; j++) acc[i][j] = (f32x4){0.f, 0.f, 0.f, 0.f};

  bf16x8 bpf[2][8];
  {
    const u16* bp = g_wbF + ((ks0 >> 5) << 13);
#pragma unroll
    for (int kk = 0; kk < 2; kk++)
#pragma unroll
      for (int jn = 0; jn < 8; jn++)
        bpf[kk][jn] = *(const bf16x8*)(bp + (kk << 13) + bofs[jn]);
  }

  for (int st = 0; st < NSTAGE; st++) {
    int k0 = ks0 + st * 64;
    int kp = k0 >> 8, ic0 = k0 & 255;
    int ky = kp / 9, kx = kp - ky * 9;
    int off = ky * 5120 + kx * 256 + ic0;
    __syncthreads();   // all waves done reading previous stage
    __builtin_amdgcn_global_load_lds(
        (const __attribute__((address_space(1))) unsigned*)(g_x1b + fixed0 + off),
        (__attribute__((address_space(3))) unsigned*)lds0, 16, 0, 0);
    __builtin_amdgcn_global_load_lds(
        (const __attribute__((address_space(1))) unsigned*)(g_x1b + fixed1 + off),
        (__attribute__((address_space(3))) unsigned*)lds1, 16, 0, 0);
    __syncthreads();   // vmcnt drain -> As ready
    // compute with B prefetched last iteration (bpf), A from swizzled LDS
#pragma unroll
    for (int kk = 0; kk < 2; kk++) {
#pragma unroll
      for (int i = 0; i < 2; i++) {
        int rr = wm * 32 + i * 16 + c15;
        int pch = (kk * 4 + quad) ^ (rr & 7);
        bf16x8 af = *(const bf16x8*)&As[rr * 64 + pch * 8];
#pragma unroll
        for (int jn = 0; jn < 8; jn++)
          acc[i][jn] = __builtin_amdgcn_mfma_f32_16x16x32_bf16(af, bpf[kk][jn], acc[i][jn], 0, 0, 0);
      }
    }
    // B prefetch one stage ahead (L2-resident, short latency)
    if (st < NSTAGE - 1) {
      int k0n = ks0 + (st + 1) * 64;
      const u16* bp = g_wbF + ((k0n >> 5) << 13);
#pragma unroll
      for (int kk = 0; kk < 2; kk++)
#pragma unroll
        for (int jn = 0; jn < 8; jn++)
          bpf[kk][jn] = *(const bf16x8*)(bp + (kk << 13) + bofs[jn]);
    }
  }
  // epilogue: C/D map col=lane&15, row=quad*4+reg
#pragma unroll
  for (int i = 0; i < 2; i++)
#pragma unroll
    for (int g = 0; g < 2; g++)
#pragma unroll
      for (int jn = 0; jn < 4; jn++) {
        int col = g * 128 + wn * 64 + jn * 16 + c15;
#pragma unroll
        for (int rg = 0; rg < 4; rg++) {
          int row = m0 + wm * 32 + i * 16 + quad * 4 + rg;
          outp[(size_t)row * 256 + col] = f2bf(acc[i][g * 4 + jn][rg]);
        }
      }
}

// ---------------- squash primary capsules (coalesced row-wise) -------------
__global__ __launch_bounds__(256) void squash_u_k(const float* __restrict__ pcb) {
  __shared__ float xs[256];
  __shared__ float scs[32];
  int m = blockIdx.x;          // 0..9215
  int t = threadIdx.x;
  int b = m / 36;
  int s = m - b * 36;
  float x = pcb[t];
  const u16* base = g_y2p + (size_t)m * 256 + t;
#pragma unroll
  for (int q = 0; q < KSPLIT; q++) x += bf2f(base[(size_t)q * PS]);
  xs[t] = x;
  __syncthreads();
  if (t < 32) {
    float sq = 0.f;
#pragma unroll
    for (int p = 0; p < 8; p++) {
      float v = xs[t + p * 32];
      sq = fmaf(v, v, sq);
    }
    scs[t] = (sq / (1.f + sq)) * rsqrtf(sq + 1e-7f);
  }
  __syncthreads();
  int g = t & 31, p = t >> 5;
  g_u[((size_t)b * 1152 + g * 36 + s) * 8 + p] = x * scs[g];
}

// ---------------- WU einsum (bf16 output) ----------------
__global__ __launch_bounds__(256) void wu_k(const float* __restrict__ W) {
  __shared__ float W_s[8][161];
  __shared__ float u_s[32][8];
  int n = blockIdx.x;
  int b0 = blockIdx.y * 32;
  int t = threadIdx.x;
  const float* Wn = W + (size_t)n * 1280;
  for (int i = t; i < 1280; i += 256) {
    int cd = i >> 3, p = i & 7;
    W_s[p][cd] = Wn[i];
  }
  {
    int bl = t >> 3, p = t & 7;
    u_s[bl][p] = g_u[(size_t)(b0 + bl) * 9216 + n * 8 + p];
  }
  __syncthreads();
#pragma unroll
  for (int i = 0; i < 20; i++) {
    int idx = t + 256 * i;
    int bl = idx / 160;
    int cd = idx - bl * 160;
    float acc = 0.f;
#pragma unroll
    for (int p = 0; p < 8; p++) acc = fmaf(u_s[bl][p], W_s[p][cd], acc);
    g_WU[((size_t)(b0 + bl) * 1152 + n) * 160 + cd] = f2bf(acc);
  }
}

// ---------------- iter0 reduction (bf16 input) ----------------
__global__ __launch_bounds__(256) void red0_k() {
  int b = blockIdx.x;
  int chunk = blockIdx.y;
  int t = threadIdx.x;
  if (t >= 160) return;
  const u16* base = g_WU + ((size_t)b * 1152 + chunk * 144) * 160 + t;
  float acc = 0.f;
  for (int n = 0; n < 144; n++) acc += bf2f(base[(size_t)n * 160]);
  atomicAdd(&g_ssum[b * 160 + t], 0.1f * acc);
}

// ---------------- squash of class capsules ----------------
__global__ void squash_v_k(int slot, float* __restrict__ clf, int write_clf) {
  int b = blockIdx.x;
  int c = threadIdx.x;
  if (c >= 10) return;
  const float* s = g_ssum + slot * 40960 + b * 160 + c * 16;
  float sq = 0.f;
#pragma unroll
  for (int d = 0; d < 16; d++) sq = fmaf(s[d], s[d], sq);
  float scale = (sq / (1.f + sq)) * rsqrtf(sq + 1e-7f);
  float* vo = g_v + slot * 40960 + b * 160 + c * 16;
#pragma unroll
  for (int d = 0; d < 16; d++) vo[d] = s[d] * scale;
  if (write_clf) clf[b * 10 + c] = scale * sqrtf(sq);
}

// ---------------- routing iteration (bf16 WU input) ----------------
template <int IT>
__global__ __launch_bounds__(256) void routing_iter_k() {
  int b = blockIdx.x;
  int nb = blockIdx.y;
  int t = threadIdx.x;
  int lane = t & 15;
  int grp = t >> 4;

  const float* v0 = g_v;
  const float* v1 = g_v + 40960;
  float* ssum_out = g_ssum + IT * 40960;

  float v0r[10], v1r[10];
#pragma unroll
  for (int c = 0; c < 10; c++) v0r[c] = v0[b * 160 + c * 16 + lane];
  if (IT == 2) {
#pragma unroll
    for (int c = 0; c < 10; c++) v1r[c] = v1[b * 160 + c * 16 + lane];
  }

  float acc[10];
#pragma unroll
  for (int c = 0; c < 10; c++) acc[c] = 0.f;

  for (int ni = 0; ni < 9; ni++) {
    int n = nb * 144 + grp * 9 + ni;
    const u16* row = g_WU + ((size_t)b * 1152 + n) * 160;
    float wu[10];
#pragma unroll
    for (int c = 0; c < 10; c++) wu[c] = bf2f(row[c * 16 + lane]);

    float bij[10];
#pragma unroll
    for (int c = 0; c < 10; c++) {
      float x = v0r[c] * wu[c];
      x += __shfl_xor(x, 1);
      x += __shfl_xor(x, 2);
      x += __shfl_xor(x, 4);
      x += __shfl_xor(x, 8);
      bij[c] = 0.1f * x;
    }

    if (IT == 2) {
      float mx = bij[0];
#pragma unroll
      for (int c = 1; c < 10; c++) mx = fmaxf(mx, bij[c]);
      float e[10], ssum = 0.f;
#pragma unroll
      for (int c = 0; c < 10; c++) {
        e[c] = __expf(bij[c] - mx);
        ssum += e[c];
      }
      float inv = 1.f / ssum;
#pragma unroll
      for (int c = 0; c < 10; c++) {
        float x = v1r[c] * wu[c];
        x += __shfl_xor(x, 1);
        x += __shfl_xor(x, 2);
        x += __shfl_xor(x, 4);
        x += __shfl_xor(x, 8);
        bij[c] = bij[c] + (e[c] * inv) * x;
      }
    }

    float mx = bij[0];
#pragma unroll
    for (int c = 1; c < 10; c++) mx = fmaxf(mx, bij[c]);
    float e[10], ssum = 0.f;
#pragma unroll
    for (int c = 0; c < 10; c++) {
      e[c] = __expf(bij[c] - mx);
      ssum += e[c];
    }
    float inv = 1.f / ssum;
#pragma unroll
    for (int c = 0; c < 10; c++) acc[c] = fmaf(e[c] * inv, wu[c], acc[c]);
  }
#pragma unroll
  for (int c = 0; c < 10; c++)
    atomicAdd(&ssum_out[b * 160 + c * 16 + lane], acc[c]);
}

// ---------------- decoder ----------------
__global__ __launch_bounds__(256) void dec1_k(const int* __restrict__ labels,
                                              const float* __restrict__ w1,
                                              const float* __restrict__ b1) {
  int b = blockIdx.y;
  int j = blockIdx.x * 256 + threadIdx.x;
  int lab = labels[b];
  const float* vv = g_v + 2 * 40960 + b * 160 + lab * 16;
  float acc = b1[j];
#pragma unroll
  for (int d = 0; d < 16; d++)
    acc = fmaf(vv[d], w1[(size_t)(lab * 16 + d) * 512 + j], acc);
  g_h1[b * 512 + j] = fmaxf(acc, 0.f);
}

// dec2: 2 batches per block — w2 stream reused 2x. Grid (4, 128).
__global__ __launch_bounds__(256) void dec2_k(const float* __restrict__ w2,
                                              const float* __restrict__ b2) {
  __shared__ float h_s[2][512];
  int b0 = blockIdx.y * 2;
  int j = blockIdx.x * 256 + threadIdx.x;
  int t = threadIdx.x;
  for (int i = t; i < 1024; i += 256) h_s[i >> 9][i & 511] = g_h1[b0 * 512 + i];
  __syncthreads();
  float a0 = b2[j], a1 = a0;
#pragma unroll 8
  for (int k = 0; k < 512; k++) {
    float wv = w2[(size_t)k * 1024 + j];
    a0 = fmaf(h_s[0][k], wv, a0);
    a1 = fmaf(h_s[1][k], wv, a1);
  }
  g_h2[b0 * 1024 + j] = fmaxf(a0, 0.f);
  g_h2[(b0 + 1) * 1024 + j] = fmaxf(a1, 0.f);
}

// dec3: 2 batches per block — w3 stream reused 2x. Grid (4, 128).
__global__ __launch_bounds__(256) void dec3_k(const float* __restrict__ w3,
                                              const float* __restrict__ b3,
                                              float* __restrict__ out) {
  __shared__ float h_s[2][1024];
  int b0 = blockIdx.y * 2;
  int t = threadIdx.x;
  for (int i = t; i < 2048; i += 256) h_s[i >> 10][i & 1023] = g_h2[b0 * 1024 + i];
  __syncthreads();
  if (t >= 196) return;
  int j = blockIdx.x * 196 + t;
  float a0 = b3[j], a1 = a0;
#pragma unroll 8
  for (int k = 0; k < 1024; k++) {
    float wv = w3[(size_t)k * 784 + j];
    a0 = fmaf(h_s[0][k], wv, a0);
    a1 = fmaf(h_s[1][k], wv, a1);
  }
  out[2560 + b0 * 784 + j] = 1.f / (1.f + __expf(-a0));
  out[2560 + (b0 + 1) * 784 + j] = 1.f / (1.f + __expf(-a1));
}

// ---------------------------------------------------------------------------
extern "C" void kernel_launch(void* const* d_in, const int* in_sizes, int n_in,
                              void* d_out, int out_size, void* d_ws,
                              size_t ws_size, hipStream_t stream) {
  const float* inputs = (const float*)d_in[0];
  const int* labels = (const int*)d_in[1];
  const float* conv1_w = (const float*)d_in[2];
  const float* conv1_b = (const float*)d_in[3];
  const float* pc_w = (const float*)d_in[4];
  const float* pc_b = (const float*)d_in[5];
  const float* rw = (const float*)d_in[6];
  const float* dw1 = (const float*)d_in[7];
  const float* db1 = (const float*)d_in[8];
  const float* dw2 = (const float*)d_in[9];
  const float* db2 = (const float*)d_in[10];
  const float* dw3 = (const float*)d_in[11];
  const float* db3 = (const float*)d_in[12];
  float* out = (float*)d_out;
  (void)d_ws; (void)ws_size; (void)in_sizes; (void)n_in;

  zero_ssum_k<<<(3 * 256 * 160 + 255) / 256, 256, 0, stream>>>();
  wconv_k<<<dim3(16, 81), 256, 0, stream>>>(pc_w);
  wb1_k<<<96, 256, 0, stream>>>(conv1_w);
  im2col_k<<<dim3(256, 2), 256, 0, stream>>>(inputs);
  conv1_mfma_k<<<1600, 256, 0, stream>>>(conv1_b);
  pc_mfma_k<<<dim3(144, KSPLIT), 256, 0, stream>>>();
  squash_u_k<<<9216, 256, 0, stream>>>(pc_b);
  wu_k<<<dim3(1152, 8), 256, 0, stream>>>(rw);
  red0_k<<<dim3(256, 8), 256, 0, stream>>>();
  squash_v_k<<<256, 64, 0, stream>>>(0, nullptr, 0);
  routing_iter_k<1><<<dim3(256, 8), 256, 0, stream>>>();
  squash_v_k<<<256, 64, 0, stream>>>(1, nullptr, 0);
  routing_iter_k<2><<<dim3(256, 8), 256, 0, stream>>>();
  squash_v_k<<<256, 64, 0, stream>>>(2, out, 1);
  dec1_k<<<dim3(2, 256), 256, 0, stream>>>(labels, dw1, db1);
  dec2_k<<<dim3(4, 128), 256, 0, stream>>>(dw2, db2);
  dec3_k<<<dim3(4, 128), 256, 0, stream>>>(dw3, db3, out);
}

// Round 2
// 621.584 us; speedup vs baseline: 1.2458x; 1.0362x over previous
//
#include <hip/hip_runtime.h>
#include <math.h>

// ---------------------------------------------------------------------------
// CapsuleNet forward. R21: pc_mfma_k restructured for L2-BW + latency:
//  (a) wave->column-quarter remap: each of 4 waves owns 64 cols x all 64 rows,
//      eliminating the 2x duplicate B-fragment loads (B L2 traffic halved,
//      was ~19.5 TB/s = 57% of L2 ceiling).
//  (b) double-buffered LDS A staging with counted s_waitcnt vmcnt(N) + raw
//      s_barrier (T3/T4 minimum 2-phase): next stage's global_load_lds stays
//      in flight across compute instead of a vmcnt(0) drain per stage.
// Issue order per wave is pinned with asm memory clobbers so the count is
// exact: window = A(st)[2], B(st)[8], A(st+1)[2] -> vmcnt(10) retires A(st).
// Everything else identical to R20 (644us).
// ---------------------------------------------------------------------------

typedef unsigned short u16;
typedef short bf16x8 __attribute__((ext_vector_type(8)));
typedef float f32x4 __attribute__((ext_vector_type(4)));

#define PS 2359296   // 9216*256, one y2 partial buffer
#define KSPLIT 9
#define KSLICE 2304  // 20736/9
#define NSTAGE 36    // 2304/64

__device__ u16 g_x1b[256 * 400 * 256];          // conv1 out NHWC bf16 (52 MB)
__device__ u16 g_wbF[648 * 16 * 512];           // pc_w bf16, MFMA frag order (10.6 MB)
__device__ u16 g_y2p[(size_t)KSPLIT * PS];      // pc GEMM K-partials bf16 (42.5 MB)
__device__ float g_u[256 * 1152 * 8];           // squashed primary caps
__device__ u16 g_WU[(size_t)256 * 1152 * 160];  // u_hat bf16 (94.4 MB)
__device__ float g_ssum[3 * 256 * 160];
__device__ float g_v[3 * 256 * 160];
__device__ float g_h1[256 * 512];
__device__ float g_h2[256 * 1024];

// conv1-as-GEMM buffers
__device__ __attribute__((aligned(256))) u16 g_im2[(size_t)102400 * 104];  // im2col bf16, 104-padded rows (21.3 MB)
__device__ __attribute__((aligned(256))) u16 g_wb1[48 * 512];              // conv1_w frags (48 KB)

__device__ __forceinline__ u16 f2bf(float f) {
  union { float f; unsigned u; } v; v.f = f;
  unsigned r = (v.u + 0x7FFFu + ((v.u >> 16) & 1u)) >> 16;  // RNE
  return (u16)r;
}
__device__ __forceinline__ float bf2f(u16 h) {
  union { unsigned u; float f; } v; v.u = ((unsigned)h) << 16;
  return v.f;
}

// ---------------- zero the atomic accumulators ----------------
__global__ __launch_bounds__(256) void zero_ssum_k() {
  int i = blockIdx.x * 256 + threadIdx.x;
  if (i < 3 * 256 * 160) g_ssum[i] = 0.f;
}

// ------ pc_w fp32 [oc][ic][kp] -> bf16 fragment order --------------------
__global__ __launch_bounds__(256) void wconv_k(const float* __restrict__ w) {
  __shared__ float Ws[256 * 16];   // [ic][ocl] 16 KB
  int n16 = blockIdx.x;   // 0..15
  int kp = blockIdx.y;    // 0..80
  int t = threadIdx.x;
  for (int idx = t; idx < 4096; idx += 256) {
    int ic = idx >> 4;
    int ocl = idx & 15;
    Ws[idx] = w[(size_t)(n16 * 16 + ocl) * 20736 + ic * 81 + kp];
  }
  __syncthreads();
  for (int idx = t; idx < 4096; idx += 256) {
    int c = idx >> 9;          // k-chunk within this kp: 0..7
    int r = idx & 511;
    int ll = r >> 3, j = r & 7;
    int ic = c * 32 + ((ll >> 4) << 3) + j;
    g_wbF[(((size_t)kp * 8 + c) * 16 + n16) * 512 + r] = f2bf(Ws[ic * 16 + (ll & 15)]);
  }
}

// ------ conv1_w fp32 [oc][81] -> bf16 MFMA B-fragment order ----------------
__global__ __launch_bounds__(256) void wb1_k(const float* __restrict__ w) {
  int idx = blockIdx.x * 256 + threadIdx.x;   // 0..24575
  int frag = idx >> 9;     // kc*16 + n16
  int r = idx & 511;
  int ll = r >> 3, j = r & 7;
  int kc = frag >> 4, n16 = frag & 15;
  int k = kc * 32 + ((ll >> 4) << 3) + j;
  int oc = n16 * 16 + (ll & 15);
  float v = (k < 81) ? w[oc * 81 + k] : 0.f;
  g_wb1[idx] = f2bf(v);
}

// ------ im2col: input fp32 [b][28][28] -> bf16 patches [m][104] ------------
__global__ __launch_bounds__(256) void im2col_k(const float* __restrict__ in) {
  __shared__ u16 im_s[784];
  int b = blockIdx.x;
  int t = threadIdx.x;
  for (int i = t; i < 784; i += 256) im_s[i] = f2bf(in[b * 784 + i]);
  __syncthreads();
  u16* outp = g_im2 + (size_t)b * 41600;   // 400*104
  int base = blockIdx.y * 2600;            // octet halves (5200 octets/image)
  for (int ii = t; ii < 2600; ii += 256) {
    int idx = base + ii;
    int p = idx / 13;                      // pixel 0..399
    int ko = (idx - p * 13) * 8;           // 0,8,...,96
    int oy = p / 20, ox = p - oy * 20;
    bf16x8 v;
#pragma unroll
    for (int e = 0; e < 8; e++) {
      int k = ko + e;
      u16 x = 0;
      if (k < 81) {
        int ky = k / 9, kx = k - ky * 9;
        x = im_s[(oy + ky) * 28 + ox + kx];
      }
      v[e] = (short)x;
    }
    *(bf16x8*)(outp + (size_t)p * 104 + ko) = v;   // 16B aligned (208B rows)
  }
}

// ------ conv1 as MFMA GEMM: M=102400, N=256, K=96 --------------------------
__global__ __launch_bounds__(256) void conv1_mfma_k(const float* __restrict__ bias) {
  int t = threadIdx.x;
  int wq = t >> 6;          // wave's oc-quarter
  int l = t & 63;
  int q = l >> 4, c15 = l & 15;
  int m0 = blockIdx.x * 64;

  // B fragments: 3 kc x 4 n16 (this wave's quarter)
  bf16x8 bf[3][4];
#pragma unroll
  for (int kc = 0; kc < 3; kc++)
#pragma unroll
    for (int jn = 0; jn < 4; jn++)
      bf[kc][jn] = *(const bf16x8*)&g_wb1[((kc * 16 + wq * 4 + jn) << 9) + l * 8];

  // A fragments: 4 m-tiles x 3 kc
  bf16x8 af[4][3];
#pragma unroll
  for (int mt = 0; mt < 4; mt++) {
    const u16* ap = g_im2 + (size_t)(m0 + mt * 16 + c15) * 104 + q * 8;
#pragma unroll
    for (int kc = 0; kc < 3; kc++)
      af[mt][kc] = *(const bf16x8*)(ap + kc * 32);
  }

  f32x4 acc[4][4];
#pragma unroll
  for (int mt = 0; mt < 4; mt++)
#pragma unroll
    for (int jn = 0; jn < 4; jn++) acc[mt][jn] = (f32x4){0.f, 0.f, 0.f, 0.f};

#pragma unroll
  for (int kc = 0; kc < 3; kc++)
#pragma unroll
    for (int mt = 0; mt < 4; mt++)
#pragma unroll
      for (int jn = 0; jn < 4; jn++)
        acc[mt][jn] = __builtin_amdgcn_mfma_f32_16x16x32_bf16(af[mt][kc], bf[kc][jn], acc[mt][jn], 0, 0, 0);

  float bv[4];
#pragma unroll
  for (int jn = 0; jn < 4; jn++) bv[jn] = bias[wq * 64 + jn * 16 + c15];

#pragma unroll
  for (int mt = 0; mt < 4; mt++) {
#pragma unroll
    for (int rg = 0; rg < 4; rg++) {
      int row = m0 + mt * 16 + q * 4 + rg;
      int b = row / 400;
      int p = row - b * 400;
      u16* ob = g_x1b + (size_t)b * 102400 + p * 256;
#pragma unroll
      for (int jn = 0; jn < 4; jn++) {
        int col = wq * 64 + jn * 16 + c15;
        ob[col] = f2bf(fmaxf(acc[mt][jn][rg] + bv[jn], 0.f));
      }
    }
  }
}

// ---- pc conv: bf16 MFMA GEMM, dedup B (col-quarter waves) + dbuf pipeline --
__global__ __launch_bounds__(256) void pc_mfma_k() {
  __shared__ u16 As[2][64 * 64];  // double-buffered, chunk xor-swizzled by row&7
  int t = threadIdx.x;
  int m0 = blockIdx.x * 64;
  int ks0 = blockIdx.y * KSLICE;
  u16* outp = g_y2p + (size_t)blockIdx.y * PS;

  int w = t >> 6, l = t & 63, quad = l >> 4, c15 = l & 15;

  // A staging: thread t fills physical chunk (t&7) of rows sr and sr+32;
  // content = logical chunk (t&7)^(sr&7) (source-side xor swizzle).
  int sr = t >> 3;
  int sc = t & 7;
  int cch = sc ^ (sr & 7);
  int fixed0, fixed1;
  {
    int m = m0 + sr;
    int bb = m / 36;
    int s = m - bb * 36;
    int oy = s / 6;
    int ox = s - oy * 6;
    fixed0 = bb * 102400 + oy * 10240 + ox * 512 + cch * 8;
    m += 32;
    bb = m / 36;
    s = m - bb * 36;
    oy = s / 6;
    ox = s - oy * 6;
    fixed1 = bb * 102400 + oy * 10240 + ox * 512 + cch * 8;
  }

  // B fragment offsets: wave w owns cols [w*64, w*64+64) -> n16 = w*4+jn
  int bofs[4];
#pragma unroll
  for (int jn = 0; jn < 4; jn++) bofs[jn] = ((w * 4 + jn) << 9) + l * 8;

  f32x4 acc[4][4];
#pragma unroll
  for (int i = 0; i < 4; i++)
#pragma unroll
    for (int j = 0; j < 4; j++) acc[i][j] = (f32x4){0.f, 0.f, 0.f, 0.f};

  bf16x8 bpf[2][4];

  // issue stage st's A loads into buffer buf (2 x global_load_lds, 16B each)
  auto STAGE = [&](int st, int buf) {
    int k0 = ks0 + st * 64;
    int kp = k0 >> 8, ic0 = k0 & 255;
    int ky = kp / 9, kx = kp - ky * 9;
    int off = ky * 5120 + kx * 256 + ic0;
    u16* l0 = &As[buf][(t >> 6) * 512];          // wave-uniform base, lanes +16B
    u16* l1 = &As[buf][2048 + (t >> 6) * 512];
    __builtin_amdgcn_global_load_lds(
        (const __attribute__((address_space(1))) unsigned*)(g_x1b + fixed0 + off),
        (__attribute__((address_space(3))) unsigned*)l0, 16, 0, 0);
    __builtin_amdgcn_global_load_lds(
        (const __attribute__((address_space(1))) unsigned*)(g_x1b + fixed1 + off),
        (__attribute__((address_space(3))) unsigned*)l1, 16, 0, 0);
  };
  // B prefetch for stage st (8 x 16B loads, L2-resident)
  auto BPF = [&](int st) {
    const u16* bp = g_wbF + (((ks0 + st * 64) >> 5) << 13);
#pragma unroll
    for (int kk = 0; kk < 2; kk++)
#pragma unroll
      for (int jn = 0; jn < 4; jn++)
        bpf[kk][jn] = *(const bf16x8*)(bp + (kk << 13) + bofs[jn]);
  };

  STAGE(0, 0);
  asm volatile("" ::: "memory");   // pin: A(0) issued before B(0)
  BPF(0);

  for (int st = 0; st < NSTAGE; st++) {
    int buf = st & 1;
    // issue next stage's A loads, then wait for THIS stage's A only.
    // per-wave VMEM window here (oldest->newest): A(st)[2], B(st)[8], A(st+1)[2]
    if (st + 1 < NSTAGE) {
      STAGE(st + 1, buf ^ 1);
      __builtin_amdgcn_sched_barrier(0);
      asm volatile("s_waitcnt vmcnt(10)" ::: "memory");  // retire A(st)
    } else {
      __builtin_amdgcn_sched_barrier(0);
      asm volatile("s_waitcnt vmcnt(8)" ::: "memory");   // retire A(st) (no A(st+1))
    }
    __builtin_amdgcn_s_barrier();        // all waves' A(st) visible
    asm volatile("" ::: "memory");       // no LDS read hoists above the barrier

    // compute on As[buf]; B regs auto-waited by compiler
#pragma unroll
    for (int kk = 0; kk < 2; kk++) {
#pragma unroll
      for (int i = 0; i < 4; i++) {
        int rr = i * 16 + c15;
        int pch = (kk * 4 + quad) ^ (rr & 7);
        bf16x8 af = *(const bf16x8*)&As[buf][rr * 64 + pch * 8];
#pragma unroll
        for (int jn = 0; jn < 4; jn++)
          acc[i][jn] = __builtin_amdgcn_mfma_f32_16x16x32_bf16(af, bpf[kk][jn], acc[i][jn], 0, 0, 0);
      }
    }
    if (st + 1 < NSTAGE) BPF(st + 1);
    asm volatile("" ::: "memory");       // B(st+1) stays before barrier
    __builtin_amdgcn_s_barrier();        // all waves done reading As[buf]
    asm volatile("" ::: "memory");       // next STAGE stays after barrier
  }

  // epilogue: C/D map col=lane&15, row=quad*4+reg; wave w -> cols w*64..w*64+63
#pragma unroll
  for (int i = 0; i < 4; i++)
#pragma unroll
    for (int jn = 0; jn < 4; jn++) {
      int col = w * 64 + jn * 16 + c15;
#pragma unroll
      for (int rg = 0; rg < 4; rg++) {
        int row = m0 + i * 16 + quad * 4 + rg;
        outp[(size_t)row * 256 + col] = f2bf(acc[i][jn][rg]);
      }
    }
}

// ---------------- squash primary capsules (coalesced row-wise) -------------
__global__ __launch_bounds__(256) void squash_u_k(const float* __restrict__ pcb) {
  __shared__ float xs[256];
  __shared__ float scs[32];
  int m = blockIdx.x;          // 0..9215
  int t = threadIdx.x;
  int b = m / 36;
  int s = m - b * 36;
  float x = pcb[t];
  const u16* base = g_y2p + (size_t)m * 256 + t;
#pragma unroll
  for (int q = 0; q < KSPLIT; q++) x += bf2f(base[(size_t)q * PS]);
  xs[t] = x;
  __syncthreads();
  if (t < 32) {
    float sq = 0.f;
#pragma unroll
    for (int p = 0; p < 8; p++) {
      float v = xs[t + p * 32];
      sq = fmaf(v, v, sq);
    }
    scs[t] = (sq / (1.f + sq)) * rsqrtf(sq + 1e-7f);
  }
  __syncthreads();
  int g = t & 31, p = t >> 5;
  g_u[((size_t)b * 1152 + g * 36 + s) * 8 + p] = x * scs[g];
}

// ---------------- WU einsum (bf16 output) ----------------
__global__ __launch_bounds__(256) void wu_k(const float* __restrict__ W) {
  __shared__ float W_s[8][161];
  __shared__ float u_s[32][8];
  int n = blockIdx.x;
  int b0 = blockIdx.y * 32;
  int t = threadIdx.x;
  const float* Wn = W + (size_t)n * 1280;
  for (int i = t; i < 1280; i += 256) {
    int cd = i >> 3, p = i & 7;
    W_s[p][cd] = Wn[i];
  }
  {
    int bl = t >> 3, p = t & 7;
    u_s[bl][p] = g_u[(size_t)(b0 + bl) * 9216 + n * 8 + p];
  }
  __syncthreads();
#pragma unroll
  for (int i = 0; i < 20; i++) {
    int idx = t + 256 * i;
    int bl = idx / 160;
    int cd = idx - bl * 160;
    float acc = 0.f;
#pragma unroll
    for (int p = 0; p < 8; p++) acc = fmaf(u_s[bl][p], W_s[p][cd], acc);
    g_WU[((size_t)(b0 + bl) * 1152 + n) * 160 + cd] = f2bf(acc);
  }
}

// ---------------- iter0 reduction (bf16 input) ----------------
__global__ __launch_bounds__(256) void red0_k() {
  int b = blockIdx.x;
  int chunk = blockIdx.y;
  int t = threadIdx.x;
  if (t >= 160) return;
  const u16* base = g_WU + ((size_t)b * 1152 + chunk * 144) * 160 + t;
  float acc = 0.f;
  for (int n = 0; n < 144; n++) acc += bf2f(base[(size_t)n * 160]);
  atomicAdd(&g_ssum[b * 160 + t], 0.1f * acc);
}

// ---------------- squash of class capsules ----------------
__global__ void squash_v_k(int slot, float* __restrict__ clf, int write_clf) {
  int b = blockIdx.x;
  int c = threadIdx.x;
  if (c >= 10) return;
  const float* s = g_ssum + slot * 40960 + b * 160 + c * 16;
  float sq = 0.f;
#pragma unroll
  for (int d = 0; d < 16; d++) sq = fmaf(s[d], s[d], sq);
  float scale = (sq / (1.f + sq)) * rsqrtf(sq + 1e-7f);
  float* vo = g_v + slot * 40960 + b * 160 + c * 16;
#pragma unroll
  for (int d = 0; d < 16; d++) vo[d] = s[d] * scale;
  if (write_clf) clf[b * 10 + c] = scale * sqrtf(sq);
}

// ---------------- routing iteration (bf16 WU input) ----------------
template <int IT>
__global__ __launch_bounds__(256) void routing_iter_k() {
  int b = blockIdx.x;
  int nb = blockIdx.y;
  int t = threadIdx.x;
  int lane = t & 15;
  int grp = t >> 4;

  const float* v0 = g_v;
  const float* v1 = g_v + 40960;
  float* ssum_out = g_ssum + IT * 40960;

  float v0r[10], v1r[10];
#pragma unroll
  for (int c = 0; c < 10; c++) v0r[c] = v0[b * 160 + c * 16 + lane];
  if (IT == 2) {
#pragma unroll
    for (int c = 0; c < 10; c++) v1r[c] = v1[b * 160 + c * 16 + lane];
  }

  float acc[10];
#pragma unroll
  for (int c = 0; c < 10; c++) acc[c] = 0.f;

  for (int ni = 0; ni < 9; ni++) {
    int n = nb * 144 + grp * 9 + ni;
    const u16* row = g_WU + ((size_t)b * 1152 + n) * 160;
    float wu[10];
#pragma unroll
    for (int c = 0; c < 10; c++) wu[c] = bf2f(row[c * 16 + lane]);

    float bij[10];
#pragma unroll
    for (int c = 0; c < 10; c++) {
      float x = v0r[c] * wu[c];
      x += __shfl_xor(x, 1);
      x += __shfl_xor(x, 2);
      x += __shfl_xor(x, 4);
      x += __shfl_xor(x, 8);
      bij[c] = 0.1f * x;
    }

    if (IT == 2) {
      float mx = bij[0];
#pragma unroll
      for (int c = 1; c < 10; c++) mx = fmaxf(mx, bij[c]);
      float e[10], ssum = 0.f;
#pragma unroll
      for (int c = 0; c < 10; c++) {
        e[c] = __expf(bij[c] - mx);
        ssum += e[c];
      }
      float inv = 1.f / ssum;
#pragma unroll
      for (int c = 0; c < 10; c++) {
        float x = v1r[c] * wu[c];
        x += __shfl_xor(x, 1);
        x += __shfl_xor(x, 2);
        x += __shfl_xor(x, 4);
        x += __shfl_xor(x, 8);
        bij[c] = bij[c] + (e[c] * inv) * x;
      }
    }

    float mx = bij[0];
#pragma unroll
    for (int c = 1; c < 10; c++) mx = fmaxf(mx, bij[c]);
    float e[10], ssum = 0.f;
#pragma unroll
    for (int c = 0; c < 10; c++) {
      e[c] = __expf(bij[c] - mx);
      ssum += e[c];
    }
    float inv = 1.f / ssum;
#pragma unroll
    for (int c = 0; c < 10; c++) acc[c] = fmaf(e[c] * inv, wu[c], acc[c]);
  }
#pragma unroll
  for (int c = 0; c < 10; c++)
    atomicAdd(&ssum_out[b * 160 + c * 16 + lane], acc[c]);
}

// ---------------- decoder ----------------
__global__ __launch_bounds__(256) void dec1_k(const int* __restrict__ labels,
                                              const float* __restrict__ w1,
                                              const float* __restrict__ b1) {
  int b = blockIdx.y;
  int j = blockIdx.x * 256 + threadIdx.x;
  int lab = labels[b];
  const float* vv = g_v + 2 * 40960 + b * 160 + lab * 16;
  float acc = b1[j];
#pragma unroll
  for (int d = 0; d < 16; d++)
    acc = fmaf(vv[d], w1[(size_t)(lab * 16 + d) * 512 + j], acc);
  g_h1[b * 512 + j] = fmaxf(acc, 0.f);
}

// dec2: 2 batches per block — w2 stream reused 2x. Grid (4, 128).
__global__ __launch_bounds__(256) void dec2_k(const float* __restrict__ w2,
                                              const float* __restrict__ b2) {
  __shared__ float h_s[2][512];
  int b0 = blockIdx.y * 2;
  int j = blockIdx.x * 256 + threadIdx.x;
  int t = threadIdx.x;
  for (int i = t; i < 1024; i += 256) h_s[i >> 9][i & 511] = g_h1[b0 * 512 + i];
  __syncthreads();
  float a0 = b2[j], a1 = a0;
#pragma unroll 8
  for (int k = 0; k < 512; k++) {
    float wv = w2[(size_t)k * 1024 + j];
    a0 = fmaf(h_s[0][k], wv, a0);
    a1 = fmaf(h_s[1][k], wv, a1);
  }
  g_h2[b0 * 1024 + j] = fmaxf(a0, 0.f);
  g_h2[(b0 + 1) * 1024 + j] = fmaxf(a1, 0.f);
}

// dec3: 2 batches per block — w3 stream reused 2x. Grid (4, 128).
__global__ __launch_bounds__(256) void dec3_k(const float* __restrict__ w3,
                                              const float* __restrict__ b3,
                                              float* __restrict__ out) {
  __shared__ float h_s[2][1024];
  int b0 = blockIdx.y * 2;
  int t = threadIdx.x;
  for (int i = t; i < 2048; i += 256) h_s[i >> 10][i & 1023] = g_h2[b0 * 1024 + i];
  __syncthreads();
  if (t >= 196) return;
  int j = blockIdx.x * 196 + t;
  float a0 = b3[j], a1 = a0;
#pragma unroll 8
  for (int k = 0; k < 1024; k++) {
    float wv = w3[(size_t)k * 784 + j];
    a0 = fmaf(h_s[0][k], wv, a0);
    a1 = fmaf(h_s[1][k], wv, a1);
  }
  out[2560 + b0 * 784 + j] = 1.f / (1.f + __expf(-a0));
  out[2560 + (b0 + 1) * 784 + j] = 1.f / (1.f + __expf(-a1));
}

// ---------------------------------------------------------------------------
extern "C" void kernel_launch(void* const* d_in, const int* in_sizes, int n_in,
                              void* d_out, int out_size, void* d_ws,
                              size_t ws_size, hipStream_t stream) {
  const float* inputs = (const float*)d_in[0];
  const int* labels = (const int*)d_in[1];
  const float* conv1_w = (const float*)d_in[2];
  const float* conv1_b = (const float*)d_in[3];
  const float* pc_w = (const float*)d_in[4];
  const float* pc_b = (const float*)d_in[5];
  const float* rw = (const float*)d_in[6];
  const float* dw1 = (const float*)d_in[7];
  const float* db1 = (const float*)d_in[8];
  const float* dw2 = (const float*)d_in[9];
  const float* db2 = (const float*)d_in[10];
  const float* dw3 = (const float*)d_in[11];
  const float* db3 = (const float*)d_in[12];
  float* out = (float*)d_out;
  (void)d_ws; (void)ws_size; (void)in_sizes; (void)n_in;

  zero_ssum_k<<<(3 * 256 * 160 + 255) / 256, 256, 0, stream>>>();
  wconv_k<<<dim3(16, 81), 256, 0, stream>>>(pc_w);
  wb1_k<<<96, 256, 0, stream>>>(conv1_w);
  im2col_k<<<dim3(256, 2), 256, 0, stream>>>(inputs);
  conv1_mfma_k<<<1600, 256, 0, stream>>>(conv1_b);
  pc_mfma_k<<<dim3(144, KSPLIT), 256, 0, stream>>>();
  squash_u_k<<<9216, 256, 0, stream>>>(pc_b);
  wu_k<<<dim3(1152, 8), 256, 0, stream>>>(rw);
  red0_k<<<dim3(256, 8), 256, 0, stream>>>();
  squash_v_k<<<256, 64, 0, stream>>>(0, nullptr, 0);
  routing_iter_k<1><<<dim3(256, 8), 256, 0, stream>>>();
  squash_v_k<<<256, 64, 0, stream>>>(1, nullptr, 0);
  routing_iter_k<2><<<dim3(256, 8), 256, 0, stream>>>();
  squash_v_k<<<256, 64, 0, stream>>>(2, out, 1);
  dec1_k<<<dim3(2, 256), 256, 0, stream>>>(labels, dw1, db1);
  dec2_k<<<dim3(4, 128), 256, 0, stream>>>(dw2, db2);
  dec3_k<<<dim3(4, 128), 256, 0, stream>>>(dw3, db3, out);
}

// Round 3
// 612.406 us; speedup vs baseline: 1.2644x; 1.0150x over previous
//
#include <hip/hip_runtime.h>
#include <math.h>

// ---------------------------------------------------------------------------
// CapsuleNet forward. R22:
//  (a) pc_mfma_k: 3-deep LDS A-pipeline (A issued 2 stages ahead -> HBM ~900cyc
//      fully covered), ONE barrier per stage (placed after own-vmcnt wait and
//      before STAGE(st+2); 3 buffers make the overwrite hazard barrier and the
//      visibility barrier coincide), stage loop unrolled x3 for compile-time
//      buffer indices, s_setprio(1) around MFMA cluster.
//      vmcnt window per wave at stage st: A(st)[2], A(st+1)[2], B(st)[8]
//      -> vmcnt(10) retires A(st); last stage vmcnt(8).
//  (b) wconv_k: coalesced rewrite (contiguous 648-float row reads + LDS
//      transpose; old version did 4096 stride-324B scattered loads per block).
// Everything else identical to R21 (622us).
// ---------------------------------------------------------------------------

typedef unsigned short u16;
typedef short bf16x8 __attribute__((ext_vector_type(8)));
typedef float f32x4 __attribute__((ext_vector_type(4)));

#define PS 2359296   // 9216*256, one y2 partial buffer
#define KSPLIT 9
#define KSLICE 2304  // 20736/9
#define NSTAGE 36    // 2304/64

__device__ u16 g_x1b[256 * 400 * 256];          // conv1 out NHWC bf16 (52 MB)
__device__ u16 g_wbF[648 * 16 * 512];           // pc_w bf16, MFMA frag order (10.6 MB)
__device__ u16 g_y2p[(size_t)KSPLIT * PS];      // pc GEMM K-partials bf16 (42.5 MB)
__device__ float g_u[256 * 1152 * 8];           // squashed primary caps
__device__ u16 g_WU[(size_t)256 * 1152 * 160];  // u_hat bf16 (94.4 MB)
__device__ float g_ssum[3 * 256 * 160];
__device__ float g_v[3 * 256 * 160];
__device__ float g_h1[256 * 512];
__device__ float g_h2[256 * 1024];

// conv1-as-GEMM buffers
__device__ __attribute__((aligned(256))) u16 g_im2[(size_t)102400 * 104];  // im2col bf16, 104-padded rows (21.3 MB)
__device__ __attribute__((aligned(256))) u16 g_wb1[48 * 512];              // conv1_w frags (48 KB)

__device__ __forceinline__ u16 f2bf(float f) {
  union { float f; unsigned u; } v; v.f = f;
  unsigned r = (v.u + 0x7FFFu + ((v.u >> 16) & 1u)) >> 16;  // RNE
  return (u16)r;
}
__device__ __forceinline__ float bf2f(u16 h) {
  union { unsigned u; float f; } v; v.u = ((unsigned)h) << 16;
  return v.f;
}

// ---------------- zero the atomic accumulators ----------------
__global__ __launch_bounds__(256) void zero_ssum_k() {
  int i = blockIdx.x * 256 + threadIdx.x;
  if (i < 3 * 256 * 160) g_ssum[i] = 0.f;
}

// ------ pc_w fp32 [oc][ic][kp] -> bf16 fragment order (coalesced) ---------
// Block (n16, icb): handles oc in [n16*16, n16*16+16), ic in [icb*8, icb*8+8),
// all 81 kp. c = icb>>2, h = icb&3. Writes r = h*128 + llh*8 + j per kp where
// oc = n16*16 + llh, ic = c*32 + h*8 + j  (matches old mapping exactly).
__global__ __launch_bounds__(256) void wconv_k(const float* __restrict__ w) {
  __shared__ float Ws[16 * 648];   // [ocl][ic_local*81 + kp] 41.5 KB
  int n16 = blockIdx.x;   // 0..15
  int icb = blockIdx.y;   // 0..31
  int c = icb >> 2, h = icb & 3;
  int t = threadIdx.x;
#pragma unroll
  for (int ocl = 0; ocl < 16; ocl++) {
    const float* src = w + (size_t)(n16 * 16 + ocl) * 20736 + icb * 648;
    for (int i = t; i < 648; i += 256) Ws[ocl * 648 + i] = src[i];
  }
  __syncthreads();
  for (int wi = t; wi < 81 * 128; wi += 256) {
    int kp = wi >> 7;
    int r7 = wi & 127;
    int llh = r7 >> 3, j = wi & 7;
    g_wbF[(((size_t)kp * 8 + c) * 16 + n16) * 512 + h * 128 + r7] =
        f2bf(Ws[llh * 648 + j * 81 + kp]);
  }
}

// ------ conv1_w fp32 [oc][81] -> bf16 MFMA B-fragment order ----------------
__global__ __launch_bounds__(256) void wb1_k(const float* __restrict__ w) {
  int idx = blockIdx.x * 256 + threadIdx.x;   // 0..24575
  int frag = idx >> 9;     // kc*16 + n16
  int r = idx & 511;
  int ll = r >> 3, j = r & 7;
  int kc = frag >> 4, n16 = frag & 15;
  int k = kc * 32 + ((ll >> 4) << 3) + j;
  int oc = n16 * 16 + (ll & 15);
  float v = (k < 81) ? w[oc * 81 + k] : 0.f;
  g_wb1[idx] = f2bf(v);
}

// ------ im2col: input fp32 [b][28][28] -> bf16 patches [m][104] ------------
__global__ __launch_bounds__(256) void im2col_k(const float* __restrict__ in) {
  __shared__ u16 im_s[784];
  int b = blockIdx.x;
  int t = threadIdx.x;
  for (int i = t; i < 784; i += 256) im_s[i] = f2bf(in[b * 784 + i]);
  __syncthreads();
  u16* outp = g_im2 + (size_t)b * 41600;   // 400*104
  int base = blockIdx.y * 2600;            // octet halves (5200 octets/image)
  for (int ii = t; ii < 2600; ii += 256) {
    int idx = base + ii;
    int p = idx / 13;                      // pixel 0..399
    int ko = (idx - p * 13) * 8;           // 0,8,...,96
    int oy = p / 20, ox = p - oy * 20;
    bf16x8 v;
#pragma unroll
    for (int e = 0; e < 8; e++) {
      int k = ko + e;
      u16 x = 0;
      if (k < 81) {
        int ky = k / 9, kx = k - ky * 9;
        x = im_s[(oy + ky) * 28 + ox + kx];
      }
      v[e] = (short)x;
    }
    *(bf16x8*)(outp + (size_t)p * 104 + ko) = v;   // 16B aligned (208B rows)
  }
}

// ------ conv1 as MFMA GEMM: M=102400, N=256, K=96 --------------------------
__global__ __launch_bounds__(256) void conv1_mfma_k(const float* __restrict__ bias) {
  int t = threadIdx.x;
  int wq = t >> 6;          // wave's oc-quarter
  int l = t & 63;
  int q = l >> 4, c15 = l & 15;
  int m0 = blockIdx.x * 64;

  // B fragments: 3 kc x 4 n16 (this wave's quarter)
  bf16x8 bf[3][4];
#pragma unroll
  for (int kc = 0; kc < 3; kc++)
#pragma unroll
    for (int jn = 0; jn < 4; jn++)
      bf[kc][jn] = *(const bf16x8*)&g_wb1[((kc * 16 + wq * 4 + jn) << 9) + l * 8];

  // A fragments: 4 m-tiles x 3 kc
  bf16x8 af[4][3];
#pragma unroll
  for (int mt = 0; mt < 4; mt++) {
    const u16* ap = g_im2 + (size_t)(m0 + mt * 16 + c15) * 104 + q * 8;
#pragma unroll
    for (int kc = 0; kc < 3; kc++)
      af[mt][kc] = *(const bf16x8*)(ap + kc * 32);
  }

  f32x4 acc[4][4];
#pragma unroll
  for (int mt = 0; mt < 4; mt++)
#pragma unroll
    for (int jn = 0; jn < 4; jn++) acc[mt][jn] = (f32x4){0.f, 0.f, 0.f, 0.f};

#pragma unroll
  for (int kc = 0; kc < 3; kc++)
#pragma unroll
    for (int mt = 0; mt < 4; mt++)
#pragma unroll
      for (int jn = 0; jn < 4; jn++)
        acc[mt][jn] = __builtin_amdgcn_mfma_f32_16x16x32_bf16(af[mt][kc], bf[kc][jn], acc[mt][jn], 0, 0, 0);

  float bv[4];
#pragma unroll
  for (int jn = 0; jn < 4; jn++) bv[jn] = bias[wq * 64 + jn * 16 + c15];

#pragma unroll
  for (int mt = 0; mt < 4; mt++) {
#pragma unroll
    for (int rg = 0; rg < 4; rg++) {
      int row = m0 + mt * 16 + q * 4 + rg;
      int b = row / 400;
      int p = row - b * 400;
      u16* ob = g_x1b + (size_t)b * 102400 + p * 256;
#pragma unroll
      for (int jn = 0; jn < 4; jn++) {
        int col = wq * 64 + jn * 16 + c15;
        ob[col] = f2bf(fmaxf(acc[mt][jn][rg] + bv[jn], 0.f));
      }
    }
  }
}

// ---- pc conv: bf16 MFMA GEMM, 3-deep A pipeline, 1 barrier/stage ----------
__global__ __launch_bounds__(256) void pc_mfma_k() {
  __shared__ u16 As[3][64 * 64];  // triple-buffered, chunk xor-swizzled by row&7
  int t = threadIdx.x;
  int m0 = blockIdx.x * 64;
  int ks0 = blockIdx.y * KSLICE;
  u16* outp = g_y2p + (size_t)blockIdx.y * PS;

  int w = t >> 6, l = t & 63, quad = l >> 4, c15 = l & 15;

  // A staging: thread t fills physical chunk (t&7) of rows sr and sr+32;
  // content = logical chunk (t&7)^(sr&7) (source-side xor swizzle).
  int sr = t >> 3;
  int sc = t & 7;
  int cch = sc ^ (sr & 7);
  int fixed0, fixed1;
  {
    int m = m0 + sr;
    int bb = m / 36;
    int s = m - bb * 36;
    int oy = s / 6;
    int ox = s - oy * 6;
    fixed0 = bb * 102400 + oy * 10240 + ox * 512 + cch * 8;
    m += 32;
    bb = m / 36;
    s = m - bb * 36;
    oy = s / 6;
    ox = s - oy * 6;
    fixed1 = bb * 102400 + oy * 10240 + ox * 512 + cch * 8;
  }

  // B fragment offsets: wave w owns cols [w*64, w*64+64) -> n16 = w*4+jn
  int bofs[4];
#pragma unroll
  for (int jn = 0; jn < 4; jn++) bofs[jn] = ((w * 4 + jn) << 9) + l * 8;

  f32x4 acc[4][4];
#pragma unroll
  for (int i = 0; i < 4; i++)
#pragma unroll
    for (int j = 0; j < 4; j++) acc[i][j] = (f32x4){0.f, 0.f, 0.f, 0.f};

  bf16x8 bpf[2][4];

  // issue stage st's A loads into buffer buf (2 x global_load_lds, 16B each)
  auto STAGE = [&](int st, int buf) {
    int k0 = ks0 + st * 64;
    int kp = k0 >> 8, ic0 = k0 & 255;
    int ky = kp / 9, kx = kp - ky * 9;
    int off = ky * 5120 + kx * 256 + ic0;
    u16* l0 = &As[buf][(t >> 6) * 512];          // wave-uniform base, lanes +16B
    u16* l1 = &As[buf][2048 + (t >> 6) * 512];
    __builtin_amdgcn_global_load_lds(
        (const __attribute__((address_space(1))) unsigned*)(g_x1b + fixed0 + off),
        (__attribute__((address_space(3))) unsigned*)l0, 16, 0, 0);
    __builtin_amdgcn_global_load_lds(
        (const __attribute__((address_space(1))) unsigned*)(g_x1b + fixed1 + off),
        (__attribute__((address_space(3))) unsigned*)l1, 16, 0, 0);
  };
  // B prefetch for stage st (8 x 16B loads, L2-resident)
  auto BPF = [&](int st) {
    const u16* bp = g_wbF + (((ks0 + st * 64) >> 5) << 13);
#pragma unroll
    for (int kk = 0; kk < 2; kk++)
#pragma unroll
      for (int jn = 0; jn < 4; jn++)
        bpf[kk][jn] = *(const bf16x8*)(bp + (kk << 13) + bofs[jn]);
  };
  // MFMA cluster on compile-time buffer index
  auto COMPUTE = [&](int buf) {
#pragma unroll
    for (int kk = 0; kk < 2; kk++) {
#pragma unroll
      for (int i = 0; i < 4; i++) {
        int rr = i * 16 + c15;
        int pch = (kk * 4 + quad) ^ (rr & 7);
        bf16x8 af = *(const bf16x8*)&As[buf][rr * 64 + pch * 8];
#pragma unroll
        for (int jn = 0; jn < 4; jn++)
          acc[i][jn] = __builtin_amdgcn_mfma_f32_16x16x32_bf16(af, bpf[kk][jn], acc[i][jn], 0, 0, 0);
      }
    }
  };

  // prologue: A0, B0, A1 (issue order pinned)
  STAGE(0, 0);
  asm volatile("" ::: "memory");
  BPF(0);
  asm volatile("" ::: "memory");
  STAGE(1, 1);
  asm volatile("" ::: "memory");

  // main loop: stages 0..32 (11 groups of 3); buffers compile-time via unroll
  for (int mst = 0; mst < NSTAGE - 3; mst += 3) {
#pragma unroll
    for (int sub = 0; sub < 3; sub++) {
      int st = mst + sub;
      // window: A(st)[2], A(st+1)[2], B(st)[8] -> retire A(st)
      asm volatile("s_waitcnt vmcnt(10)" ::: "memory");
      __builtin_amdgcn_sched_barrier(0);
      __builtin_amdgcn_s_barrier();   // all A(st) visible; all compute(st-1) done
      asm volatile("" ::: "memory");
      STAGE(st + 2, (sub + 2) % 3);   // overwrites buffer read at st-1: safe
      asm volatile("" ::: "memory");
      __builtin_amdgcn_s_setprio(1);
      COMPUTE(sub);                   // buf = st%3 = sub
      __builtin_amdgcn_s_setprio(0);
      BPF(st + 1);
      asm volatile("" ::: "memory");
    }
  }
  // tail: st = 33 (buf 0), 34 (buf 1), 35 (buf 2)
  asm volatile("s_waitcnt vmcnt(10)" ::: "memory");
  __builtin_amdgcn_sched_barrier(0);
  __builtin_amdgcn_s_barrier();
  asm volatile("" ::: "memory");
  STAGE(35, 2);
  asm volatile("" ::: "memory");
  __builtin_amdgcn_s_setprio(1);
  COMPUTE(0);
  __builtin_amdgcn_s_setprio(0);
  BPF(34);
  asm volatile("" ::: "memory");

  asm volatile("s_waitcnt vmcnt(10)" ::: "memory");
  __builtin_amdgcn_sched_barrier(0);
  __builtin_amdgcn_s_barrier();
  asm volatile("" ::: "memory");
  __builtin_amdgcn_s_setprio(1);
  COMPUTE(1);
  __builtin_amdgcn_s_setprio(0);
  BPF(35);
  asm volatile("" ::: "memory");

  asm volatile("s_waitcnt vmcnt(8)" ::: "memory");
  __builtin_amdgcn_sched_barrier(0);
  __builtin_amdgcn_s_barrier();
  asm volatile("" ::: "memory");
  __builtin_amdgcn_s_setprio(1);
  COMPUTE(2);
  __builtin_amdgcn_s_setprio(0);

  // epilogue: C/D map col=lane&15, row=quad*4+reg; wave w -> cols w*64..w*64+63
#pragma unroll
  for (int i = 0; i < 4; i++)
#pragma unroll
    for (int jn = 0; jn < 4; jn++) {
      int col = w * 64 + jn * 16 + c15;
#pragma unroll
      for (int rg = 0; rg < 4; rg++) {
        int row = m0 + i * 16 + quad * 4 + rg;
        outp[(size_t)row * 256 + col] = f2bf(acc[i][jn][rg]);
      }
    }
}

// ---------------- squash primary capsules (coalesced row-wise) -------------
__global__ __launch_bounds__(256) void squash_u_k(const float* __restrict__ pcb) {
  __shared__ float xs[256];
  __shared__ float scs[32];
  int m = blockIdx.x;          // 0..9215
  int t = threadIdx.x;
  int b = m / 36;
  int s = m - b * 36;
  float x = pcb[t];
  const u16* base = g_y2p + (size_t)m * 256 + t;
#pragma unroll
  for (int q = 0; q < KSPLIT; q++) x += bf2f(base[(size_t)q * PS]);
  xs[t] = x;
  __syncthreads();
  if (t < 32) {
    float sq = 0.f;
#pragma unroll
    for (int p = 0; p < 8; p++) {
      float v = xs[t + p * 32];
      sq = fmaf(v, v, sq);
    }
    scs[t] = (sq / (1.f + sq)) * rsqrtf(sq + 1e-7f);
  }
  __syncthreads();
  int g = t & 31, p = t >> 5;
  g_u[((size_t)b * 1152 + g * 36 + s) * 8 + p] = x * scs[g];
}

// ---------------- WU einsum (bf16 output) ----------------
__global__ __launch_bounds__(256) void wu_k(const float* __restrict__ W) {
  __shared__ float W_s[8][161];
  __shared__ float u_s[32][8];
  int n = blockIdx.x;
  int b0 = blockIdx.y * 32;
  int t = threadIdx.x;
  const float* Wn = W + (size_t)n * 1280;
  for (int i = t; i < 1280; i += 256) {
    int cd = i >> 3, p = i & 7;
    W_s[p][cd] = Wn[i];
  }
  {
    int bl = t >> 3, p = t & 7;
    u_s[bl][p] = g_u[(size_t)(b0 + bl) * 9216 + n * 8 + p];
  }
  __syncthreads();
#pragma unroll
  for (int i = 0; i < 20; i++) {
    int idx = t + 256 * i;
    int bl = idx / 160;
    int cd = idx - bl * 160;
    float acc = 0.f;
#pragma unroll
    for (int p = 0; p < 8; p++) acc = fmaf(u_s[bl][p], W_s[p][cd], acc);
    g_WU[((size_t)(b0 + bl) * 1152 + n) * 160 + cd] = f2bf(acc);
  }
}

// ---------------- iter0 reduction (bf16 input) ----------------
__global__ __launch_bounds__(256) void red0_k() {
  int b = blockIdx.x;
  int chunk = blockIdx.y;
  int t = threadIdx.x;
  if (t >= 160) return;
  const u16* base = g_WU + ((size_t)b * 1152 + chunk * 144) * 160 + t;
  float acc = 0.f;
  for (int n = 0; n < 144; n++) acc += bf2f(base[(size_t)n * 160]);
  atomicAdd(&g_ssum[b * 160 + t], 0.1f * acc);
}

// ---------------- squash of class capsules ----------------
__global__ void squash_v_k(int slot, float* __restrict__ clf, int write_clf) {
  int b = blockIdx.x;
  int c = threadIdx.x;
  if (c >= 10) return;
  const float* s = g_ssum + slot * 40960 + b * 160 + c * 16;
  float sq = 0.f;
#pragma unroll
  for (int d = 0; d < 16; d++) sq = fmaf(s[d], s[d], sq);
  float scale = (sq / (1.f + sq)) * rsqrtf(sq + 1e-7f);
  float* vo = g_v + slot * 40960 + b * 160 + c * 16;
#pragma unroll
  for (int d = 0; d < 16; d++) vo[d] = s[d] * scale;
  if (write_clf) clf[b * 10 + c] = scale * sqrtf(sq);
}

// ---------------- routing iteration (bf16 WU input) ----------------
template <int IT>
__global__ __launch_bounds__(256) void routing_iter_k() {
  int b = blockIdx.x;
  int nb = blockIdx.y;
  int t = threadIdx.x;
  int lane = t & 15;
  int grp = t >> 4;

  const float* v0 = g_v;
  const float* v1 = g_v + 40960;
  float* ssum_out = g_ssum + IT * 40960;

  float v0r[10], v1r[10];
#pragma unroll
  for (int c = 0; c < 10; c++) v0r[c] = v0[b * 160 + c * 16 + lane];
  if (IT == 2) {
#pragma unroll
    for (int c = 0; c < 10; c++) v1r[c] = v1[b * 160 + c * 16 + lane];
  }

  float acc[10];
#pragma unroll
  for (int c = 0; c < 10; c++) acc[c] = 0.f;

  for (int ni = 0; ni < 9; ni++) {
    int n = nb * 144 + grp * 9 + ni;
    const u16* row = g_WU + ((size_t)b * 1152 + n) * 160;
    float wu[10];
#pragma unroll
    for (int c = 0; c < 10; c++) wu[c] = bf2f(row[c * 16 + lane]);

    float bij[10];
#pragma unroll
    for (int c = 0; c < 10; c++) {
      float x = v0r[c] * wu[c];
      x += __shfl_xor(x, 1);
      x += __shfl_xor(x, 2);
      x += __shfl_xor(x, 4);
      x += __shfl_xor(x, 8);
      bij[c] = 0.1f * x;
    }

    if (IT == 2) {
      float mx = bij[0];
#pragma unroll
      for (int c = 1; c < 10; c++) mx = fmaxf(mx, bij[c]);
      float e[10], ssum = 0.f;
#pragma unroll
      for (int c = 0; c < 10; c++) {
        e[c] = __expf(bij[c] - mx);
        ssum += e[c];
      }
      float inv = 1.f / ssum;
#pragma unroll
      for (int c = 0; c < 10; c++) {
        float x = v1r[c] * wu[c];
        x += __shfl_xor(x, 1);
        x += __shfl_xor(x, 2);
        x += __shfl_xor(x, 4);
        x += __shfl_xor(x, 8);
        bij[c] = bij[c] + (e[c] * inv) * x;
      }
    }

    float mx = bij[0];
#pragma unroll
    for (int c = 1; c < 10; c++) mx = fmaxf(mx, bij[c]);
    float e[10], ssum = 0.f;
#pragma unroll
    for (int c = 0; c < 10; c++) {
      e[c] = __expf(bij[c] - mx);
      ssum += e[c];
    }
    float inv = 1.f / ssum;
#pragma unroll
    for (int c = 0; c < 10; c++) acc[c] = fmaf(e[c] * inv, wu[c], acc[c]);
  }
#pragma unroll
  for (int c = 0; c < 10; c++)
    atomicAdd(&ssum_out[b * 160 + c * 16 + lane], acc[c]);
}

// ---------------- decoder ----------------
__global__ __launch_bounds__(256) void dec1_k(const int* __restrict__ labels,
                                              const float* __restrict__ w1,
                                              const float* __restrict__ b1) {
  int b = blockIdx.y;
  int j = blockIdx.x * 256 + threadIdx.x;
  int lab = labels[b];
  const float* vv = g_v + 2 * 40960 + b * 160 + lab * 16;
  float acc = b1[j];
#pragma unroll
  for (int d = 0; d < 16; d++)
    acc = fmaf(vv[d], w1[(size_t)(lab * 16 + d) * 512 + j], acc);
  g_h1[b * 512 + j] = fmaxf(acc, 0.f);
}

// dec2: 2 batches per block — w2 stream reused 2x. Grid (4, 128).
__global__ __launch_bounds__(256) void dec2_k(const float* __restrict__ w2,
                                              const float* __restrict__ b2) {
  __shared__ float h_s[2][512];
  int b0 = blockIdx.y * 2;
  int j = blockIdx.x * 256 + threadIdx.x;
  int t = threadIdx.x;
  for (int i = t; i < 1024; i += 256) h_s[i >> 9][i & 511] = g_h1[b0 * 512 + i];
  __syncthreads();
  float a0 = b2[j], a1 = a0;
#pragma unroll 8
  for (int k = 0; k < 512; k++) {
    float wv = w2[(size_t)k * 1024 + j];
    a0 = fmaf(h_s[0][k], wv, a0);
    a1 = fmaf(h_s[1][k], wv, a1);
  }
  g_h2[b0 * 1024 + j] = fmaxf(a0, 0.f);
  g_h2[(b0 + 1) * 1024 + j] = fmaxf(a1, 0.f);
}

// dec3: 2 batches per block — w3 stream reused 2x. Grid (4, 128).
__global__ __launch_bounds__(256) void dec3_k(const float* __restrict__ w3,
                                              const float* __restrict__ b3,
                                              float* __restrict__ out) {
  __shared__ float h_s[2][1024];
  int b0 = blockIdx.y * 2;
  int t = threadIdx.x;
  for (int i = t; i < 2048; i += 256) h_s[i >> 10][i & 1023] = g_h2[b0 * 1024 + i];
  __syncthreads();
  if (t >= 196) return;
  int j = blockIdx.x * 196 + t;
  float a0 = b3[j], a1 = a0;
#pragma unroll 8
  for (int k = 0; k < 1024; k++) {
    float wv = w3[(size_t)k * 784 + j];
    a0 = fmaf(h_s[0][k], wv, a0);
    a1 = fmaf(h_s[1][k], wv, a1);
  }
  out[2560 + b0 * 784 + j] = 1.f / (1.f + __expf(-a0));
  out[2560 + (b0 + 1) * 784 + j] = 1.f / (1.f + __expf(-a1));
}

// ---------------------------------------------------------------------------
extern "C" void kernel_launch(void* const* d_in, const int* in_sizes, int n_in,
                              void* d_out, int out_size, void* d_ws,
                              size_t ws_size, hipStream_t stream) {
  const float* inputs = (const float*)d_in[0];
  const int* labels = (const int*)d_in[1];
  const float* conv1_w = (const float*)d_in[2];
  const float* conv1_b = (const float*)d_in[3];
  const float* pc_w = (const float*)d_in[4];
  const float* pc_b = (const float*)d_in[5];
  const float* rw = (const float*)d_in[6];
  const float* dw1 = (const float*)d_in[7];
  const float* db1 = (const float*)d_in[8];
  const float* dw2 = (const float*)d_in[9];
  const float* db2 = (const float*)d_in[10];
  const float* dw3 = (const float*)d_in[11];
  const float* db3 = (const float*)d_in[12];
  float* out = (float*)d_out;
  (void)d_ws; (void)ws_size; (void)in_sizes; (void)n_in;

  zero_ssum_k<<<(3 * 256 * 160 + 255) / 256, 256, 0, stream>>>();
  wconv_k<<<dim3(16, 32), 256, 0, stream>>>(pc_w);
  wb1_k<<<96, 256, 0, stream>>>(conv1_w);
  im2col_k<<<dim3(256, 2), 256, 0, stream>>>(inputs);
  conv1_mfma_k<<<1600, 256, 0, stream>>>(conv1_b);
  pc_mfma_k<<<dim3(144, KSPLIT), 256, 0, stream>>>();
  squash_u_k<<<9216, 256, 0, stream>>>(pc_b);
  wu_k<<<dim3(1152, 8), 256, 0, stream>>>(rw);
  red0_k<<<dim3(256, 8), 256, 0, stream>>>();
  squash_v_k<<<256, 64, 0, stream>>>(0, nullptr, 0);
  routing_iter_k<1><<<dim3(256, 8), 256, 0, stream>>>();
  squash_v_k<<<256, 64, 0, stream>>>(1, nullptr, 0);
  routing_iter_k<2><<<dim3(256, 8), 256, 0, stream>>>();
  squash_v_k<<<256, 64, 0, stream>>>(2, out, 1);
  dec1_k<<<dim3(2, 256), 256, 0, stream>>>(labels, dw1, db1);
  dec2_k<<<dim3(4, 128), 256, 0, stream>>>(dw2, db2);
  dec3_k<<<dim3(4, 128), 256, 0, stream>>>(dw3, db3, out);
}

// Round 4
// 608.955 us; speedup vs baseline: 1.2716x; 1.0057x over previous
//
#include <hip/hip_runtime.h>
#include <math.h>

// ---------------------------------------------------------------------------
// CapsuleNet forward. R23: pc_mfma_k with
//  (a) BK=128 stages (18 instead of 36): 64 MFMAs per wave per sync point,
//      half the barriers, 2x latency cover from the 2-stage-ahead A prefetch.
//      LDS 3x16KB=48KB (3 blocks/CU), bpf[4][4]+acc -> ~160 VGPR (3 waves/SIMD,
//      matches LDS limit). Stage window never crosses a kp boundary (128|256).
//      Swizzle: 16 chunks/row, physical = logical ^ (row&15).
//      vmcnt window at stage st: A(st)[4], A(st+1)[4], B(st)[16] -> vmcnt(20);
//      last stage vmcnt(16).
//  (b) XCD-locality block remap: lin -> xcd=lin&7, slot=lin>>3, q=slot%9,
//      mb=xcd*18+slot/9. All 9 k-slices of an m-block run consecutively on ONE
//      XCD -> shared input pixels hit that XCD's L2 (FETCH was 150MB = 3x the
//      52MB unique A footprint). 1296=8*162 -> bijective.
// Everything else identical to R22 (612us).
// ---------------------------------------------------------------------------

typedef unsigned short u16;
typedef short bf16x8 __attribute__((ext_vector_type(8)));
typedef float f32x4 __attribute__((ext_vector_type(4)));

#define PS 2359296   // 9216*256, one y2 partial buffer
#define KSPLIT 9
#define KSLICE 2304  // 20736/9
#define NSTG 18      // 2304/128

__device__ u16 g_x1b[256 * 400 * 256];          // conv1 out NHWC bf16 (52 MB)
__device__ u16 g_wbF[648 * 16 * 512];           // pc_w bf16, MFMA frag order (10.6 MB)
__device__ u16 g_y2p[(size_t)KSPLIT * PS];      // pc GEMM K-partials bf16 (42.5 MB)
__device__ float g_u[256 * 1152 * 8];           // squashed primary caps
__device__ u16 g_WU[(size_t)256 * 1152 * 160];  // u_hat bf16 (94.4 MB)
__device__ float g_ssum[3 * 256 * 160];
__device__ float g_v[3 * 256 * 160];
__device__ float g_h1[256 * 512];
__device__ float g_h2[256 * 1024];

// conv1-as-GEMM buffers
__device__ __attribute__((aligned(256))) u16 g_im2[(size_t)102400 * 104];  // im2col bf16, 104-padded rows (21.3 MB)
__device__ __attribute__((aligned(256))) u16 g_wb1[48 * 512];              // conv1_w frags (48 KB)

__device__ __forceinline__ u16 f2bf(float f) {
  union { float f; unsigned u; } v; v.f = f;
  unsigned r = (v.u + 0x7FFFu + ((v.u >> 16) & 1u)) >> 16;  // RNE
  return (u16)r;
}
__device__ __forceinline__ float bf2f(u16 h) {
  union { unsigned u; float f; } v; v.u = ((unsigned)h) << 16;
  return v.f;
}

// ---------------- zero the atomic accumulators ----------------
__global__ __launch_bounds__(256) void zero_ssum_k() {
  int i = blockIdx.x * 256 + threadIdx.x;
  if (i < 3 * 256 * 160) g_ssum[i] = 0.f;
}

// ------ pc_w fp32 [oc][ic][kp] -> bf16 fragment order (coalesced) ---------
__global__ __launch_bounds__(256) void wconv_k(const float* __restrict__ w) {
  __shared__ float Ws[16 * 648];   // [ocl][ic_local*81 + kp] 41.5 KB
  int n16 = blockIdx.x;   // 0..15
  int icb = blockIdx.y;   // 0..31
  int c = icb >> 2, h = icb & 3;
  int t = threadIdx.x;
#pragma unroll
  for (int ocl = 0; ocl < 16; ocl++) {
    const float* src = w + (size_t)(n16 * 16 + ocl) * 20736 + icb * 648;
    for (int i = t; i < 648; i += 256) Ws[ocl * 648 + i] = src[i];
  }
  __syncthreads();
  for (int wi = t; wi < 81 * 128; wi += 256) {
    int kp = wi >> 7;
    int r7 = wi & 127;
    int llh = r7 >> 3, j = wi & 7;
    g_wbF[(((size_t)kp * 8 + c) * 16 + n16) * 512 + h * 128 + r7] =
        f2bf(Ws[llh * 648 + j * 81 + kp]);
  }
}

// ------ conv1_w fp32 [oc][81] -> bf16 MFMA B-fragment order ----------------
__global__ __launch_bounds__(256) void wb1_k(const float* __restrict__ w) {
  int idx = blockIdx.x * 256 + threadIdx.x;   // 0..24575
  int frag = idx >> 9;     // kc*16 + n16
  int r = idx & 511;
  int ll = r >> 3, j = r & 7;
  int kc = frag >> 4, n16 = frag & 15;
  int k = kc * 32 + ((ll >> 4) << 3) + j;
  int oc = n16 * 16 + (ll & 15);
  float v = (k < 81) ? w[oc * 81 + k] : 0.f;
  g_wb1[idx] = f2bf(v);
}

// ------ im2col: input fp32 [b][28][28] -> bf16 patches [m][104] ------------
__global__ __launch_bounds__(256) void im2col_k(const float* __restrict__ in) {
  __shared__ u16 im_s[784];
  int b = blockIdx.x;
  int t = threadIdx.x;
  for (int i = t; i < 784; i += 256) im_s[i] = f2bf(in[b * 784 + i]);
  __syncthreads();
  u16* outp = g_im2 + (size_t)b * 41600;   // 400*104
  int base = blockIdx.y * 2600;            // octet halves (5200 octets/image)
  for (int ii = t; ii < 2600; ii += 256) {
    int idx = base + ii;
    int p = idx / 13;                      // pixel 0..399
    int ko = (idx - p * 13) * 8;           // 0,8,...,96
    int oy = p / 20, ox = p - oy * 20;
    bf16x8 v;
#pragma unroll
    for (int e = 0; e < 8; e++) {
      int k = ko + e;
      u16 x = 0;
      if (k < 81) {
        int ky = k / 9, kx = k - ky * 9;
        x = im_s[(oy + ky) * 28 + ox + kx];
      }
      v[e] = (short)x;
    }
    *(bf16x8*)(outp + (size_t)p * 104 + ko) = v;   // 16B aligned (208B rows)
  }
}

// ------ conv1 as MFMA GEMM: M=102400, N=256, K=96 --------------------------
__global__ __launch_bounds__(256) void conv1_mfma_k(const float* __restrict__ bias) {
  int t = threadIdx.x;
  int wq = t >> 6;          // wave's oc-quarter
  int l = t & 63;
  int q = l >> 4, c15 = l & 15;
  int m0 = blockIdx.x * 64;

  // B fragments: 3 kc x 4 n16 (this wave's quarter)
  bf16x8 bf[3][4];
#pragma unroll
  for (int kc = 0; kc < 3; kc++)
#pragma unroll
    for (int jn = 0; jn < 4; jn++)
      bf[kc][jn] = *(const bf16x8*)&g_wb1[((kc * 16 + wq * 4 + jn) << 9) + l * 8];

  // A fragments: 4 m-tiles x 3 kc
  bf16x8 af[4][3];
#pragma unroll
  for (int mt = 0; mt < 4; mt++) {
    const u16* ap = g_im2 + (size_t)(m0 + mt * 16 + c15) * 104 + q * 8;
#pragma unroll
    for (int kc = 0; kc < 3; kc++)
      af[mt][kc] = *(const bf16x8*)(ap + kc * 32);
  }

  f32x4 acc[4][4];
#pragma unroll
  for (int mt = 0; mt < 4; mt++)
#pragma unroll
    for (int jn = 0; jn < 4; jn++) acc[mt][jn] = (f32x4){0.f, 0.f, 0.f, 0.f};

#pragma unroll
  for (int kc = 0; kc < 3; kc++)
#pragma unroll
    for (int mt = 0; mt < 4; mt++)
#pragma unroll
      for (int jn = 0; jn < 4; jn++)
        acc[mt][jn] = __builtin_amdgcn_mfma_f32_16x16x32_bf16(af[mt][kc], bf[kc][jn], acc[mt][jn], 0, 0, 0);

  float bv[4];
#pragma unroll
  for (int jn = 0; jn < 4; jn++) bv[jn] = bias[wq * 64 + jn * 16 + c15];

#pragma unroll
  for (int mt = 0; mt < 4; mt++) {
#pragma unroll
    for (int rg = 0; rg < 4; rg++) {
      int row = m0 + mt * 16 + q * 4 + rg;
      int b = row / 400;
      int p = row - b * 400;
      u16* ob = g_x1b + (size_t)b * 102400 + p * 256;
#pragma unroll
      for (int jn = 0; jn < 4; jn++) {
        int col = wq * 64 + jn * 16 + c15;
        ob[col] = f2bf(fmaxf(acc[mt][jn][rg] + bv[jn], 0.f));
      }
    }
  }
}

// ---- pc conv: bf16 MFMA GEMM, BK=128, 3-deep pipeline, XCD remap ----------
__global__ __launch_bounds__(256) void pc_mfma_k() {
  __shared__ u16 As[3][64 * 128];  // 3 x 16 KB, chunk xor-swizzled by row&15
  int t = threadIdx.x;

  // XCD-locality remap: all 9 k-slices of an m-block on one XCD, consecutive.
  int lin = blockIdx.y * 144 + blockIdx.x;   // 0..1295
  int xcd = lin & 7;
  int slot = lin >> 3;        // 0..161
  int q9 = slot % 9;
  int mb = xcd * 18 + slot / 9;

  int m0 = mb * 64;
  int ks0 = q9 * KSLICE;
  u16* outp = g_y2p + (size_t)q9 * PS;

  int w = t >> 6, l = t & 63, quad = l >> 4, c15 = l & 15;

  // A staging: issue j of wave w covers LDS slots (j*256 + w*64 + lane),
  // slot = row*16 + pch; row = j*16 + w*4 + (lane>>4), pch = lane&15.
  // Content: logical chunk cch = pch ^ (row&15); row&15 = (w*4 + lane>>4)&15
  // is j-independent.
  int cch = (l & 15) ^ ((w * 4 + (l >> 4)) & 15);
  int fixed[4];
#pragma unroll
  for (int j = 0; j < 4; j++) {
    int m = m0 + j * 16 + w * 4 + (l >> 4);
    int bb = m / 36;
    int s = m - bb * 36;
    int oy = s / 6;
    int ox = s - oy * 6;
    fixed[j] = bb * 102400 + oy * 10240 + ox * 512 + cch * 8;
  }

  // B fragment offsets: wave w owns cols [w*64, w*64+64) -> n16 = w*4+jn
  int bofs[4];
#pragma unroll
  for (int jn = 0; jn < 4; jn++) bofs[jn] = ((w * 4 + jn) << 9) + l * 8;

  f32x4 acc[4][4];
#pragma unroll
  for (int i = 0; i < 4; i++)
#pragma unroll
    for (int j = 0; j < 4; j++) acc[i][j] = (f32x4){0.f, 0.f, 0.f, 0.f};

  bf16x8 bpf[4][4];

  // issue stage st's A loads into buffer buf (4 x global_load_lds, 16B each)
  auto STAGE = [&](int st, int buf) {
    int k0 = ks0 + st * 128;
    int kp = k0 >> 8, ic0 = k0 & 255;     // window never crosses kp (128|256)
    int ky = kp / 9, kx = kp - ky * 9;
    int off = ky * 5120 + kx * 256 + ic0;
#pragma unroll
    for (int j = 0; j < 4; j++) {
      u16* ldsb = &As[buf][j * 2048 + w * 512];   // wave-uniform base
      __builtin_amdgcn_global_load_lds(
          (const __attribute__((address_space(1))) unsigned*)(g_x1b + fixed[j] + off),
          (__attribute__((address_space(3))) unsigned*)ldsb, 16, 0, 0);
    }
  };
  // B prefetch for stage st (16 x 16B loads, L2-resident)
  auto BPF = [&](int st) {
    size_t cb = (size_t)((ks0 + st * 128) >> 5);
    const u16* bp = g_wbF + (cb << 13);
#pragma unroll
    for (int kk = 0; kk < 4; kk++)
#pragma unroll
      for (int jn = 0; jn < 4; jn++)
        bpf[kk][jn] = *(const bf16x8*)(bp + ((size_t)kk << 13) + bofs[jn]);
  };
  // MFMA cluster on compile-time buffer index
  auto COMPUTE = [&](int buf) {
#pragma unroll
    for (int kk = 0; kk < 4; kk++) {
#pragma unroll
      for (int i = 0; i < 4; i++) {
        int rr = i * 16 + c15;
        int pch = (kk * 4 + quad) ^ c15;     // rr&15 == c15
        bf16x8 af = *(const bf16x8*)&As[buf][rr * 128 + pch * 8];
#pragma unroll
        for (int jn = 0; jn < 4; jn++)
          acc[i][jn] = __builtin_amdgcn_mfma_f32_16x16x32_bf16(af, bpf[kk][jn], acc[i][jn], 0, 0, 0);
      }
    }
  };

  // prologue: A0, B0, A1 (issue order pinned)
  STAGE(0, 0);
  asm volatile("" ::: "memory");
  BPF(0);
  asm volatile("" ::: "memory");
  STAGE(1, 1);
  asm volatile("" ::: "memory");

  // main loop: stages 0..14 (5 groups of 3); buffers compile-time via unroll
  for (int mst = 0; mst < NSTG - 3; mst += 3) {
#pragma unroll
    for (int sub = 0; sub < 3; sub++) {
      int st = mst + sub;
      // window: A(st)[4], A(st+1)[4], B(st)[16] -> retire A(st)
      asm volatile("s_waitcnt vmcnt(20)" ::: "memory");
      __builtin_amdgcn_sched_barrier(0);
      __builtin_amdgcn_s_barrier();   // all A(st) visible; all compute(st-1) done
      asm volatile("" ::: "memory");
      STAGE(st + 2, (sub + 2) % 3);   // overwrites buffer read at st-1: safe
      asm volatile("" ::: "memory");
      __builtin_amdgcn_s_setprio(1);
      COMPUTE(sub);                   // buf = st%3 = sub
      __builtin_amdgcn_s_setprio(0);
      BPF(st + 1);
      asm volatile("" ::: "memory");
    }
  }
  // tail: st = 15 (buf 0), 16 (buf 1), 17 (buf 2)
  asm volatile("s_waitcnt vmcnt(20)" ::: "memory");
  __builtin_amdgcn_sched_barrier(0);
  __builtin_amdgcn_s_barrier();
  asm volatile("" ::: "memory");
  STAGE(17, 2);
  asm volatile("" ::: "memory");
  __builtin_amdgcn_s_setprio(1);
  COMPUTE(0);
  __builtin_amdgcn_s_setprio(0);
  BPF(16);
  asm volatile("" ::: "memory");

  asm volatile("s_waitcnt vmcnt(20)" ::: "memory");
  __builtin_amdgcn_sched_barrier(0);
  __builtin_amdgcn_s_barrier();
  asm volatile("" ::: "memory");
  __builtin_amdgcn_s_setprio(1);
  COMPUTE(1);
  __builtin_amdgcn_s_setprio(0);
  BPF(17);
  asm volatile("" ::: "memory");

  asm volatile("s_waitcnt vmcnt(16)" ::: "memory");
  __builtin_amdgcn_sched_barrier(0);
  __builtin_amdgcn_s_barrier();
  asm volatile("" ::: "memory");
  __builtin_amdgcn_s_setprio(1);
  COMPUTE(2);
  __builtin_amdgcn_s_setprio(0);

  // epilogue: C/D map col=lane&15, row=quad*4+reg; wave w -> cols w*64..w*64+63
#pragma unroll
  for (int i = 0; i < 4; i++)
#pragma unroll
    for (int jn = 0; jn < 4; jn++) {
      int col = w * 64 + jn * 16 + c15;
#pragma unroll
      for (int rg = 0; rg < 4; rg++) {
        int row = m0 + i * 16 + quad * 4 + rg;
        outp[(size_t)row * 256 + col] = f2bf(acc[i][jn][rg]);
      }
    }
}

// ---------------- squash primary capsules (coalesced row-wise) -------------
__global__ __launch_bounds__(256) void squash_u_k(const float* __restrict__ pcb) {
  __shared__ float xs[256];
  __shared__ float scs[32];
  int m = blockIdx.x;          // 0..9215
  int t = threadIdx.x;
  int b = m / 36;
  int s = m - b * 36;
  float x = pcb[t];
  const u16* base = g_y2p + (size_t)m * 256 + t;
#pragma unroll
  for (int q = 0; q < KSPLIT; q++) x += bf2f(base[(size_t)q * PS]);
  xs[t] = x;
  __syncthreads();
  if (t < 32) {
    float sq = 0.f;
#pragma unroll
    for (int p = 0; p < 8; p++) {
      float v = xs[t + p * 32];
      sq = fmaf(v, v, sq);
    }
    scs[t] = (sq / (1.f + sq)) * rsqrtf(sq + 1e-7f);
  }
  __syncthreads();
  int g = t & 31, p = t >> 5;
  g_u[((size_t)b * 1152 + g * 36 + s) * 8 + p] = x * scs[g];
}

// ---------------- WU einsum (bf16 output) ----------------
__global__ __launch_bounds__(256) void wu_k(const float* __restrict__ W) {
  __shared__ float W_s[8][161];
  __shared__ float u_s[32][8];
  int n = blockIdx.x;
  int b0 = blockIdx.y * 32;
  int t = threadIdx.x;
  const float* Wn = W + (size_t)n * 1280;
  for (int i = t; i < 1280; i += 256) {
    int cd = i >> 3, p = i & 7;
    W_s[p][cd] = Wn[i];
  }
  {
    int bl = t >> 3, p = t & 7;
    u_s[bl][p] = g_u[(size_t)(b0 + bl) * 9216 + n * 8 + p];
  }
  __syncthreads();
#pragma unroll
  for (int i = 0; i < 20; i++) {
    int idx = t + 256 * i;
    int bl = idx / 160;
    int cd = idx - bl * 160;
    float acc = 0.f;
#pragma unroll
    for (int p = 0; p < 8; p++) acc = fmaf(u_s[bl][p], W_s[p][cd], acc);
    g_WU[((size_t)(b0 + bl) * 1152 + n) * 160 + cd] = f2bf(acc);
  }
}

// ---------------- iter0 reduction (bf16 input) ----------------
__global__ __launch_bounds__(256) void red0_k() {
  int b = blockIdx.x;
  int chunk = blockIdx.y;
  int t = threadIdx.x;
  if (t >= 160) return;
  const u16* base = g_WU + ((size_t)b * 1152 + chunk * 144) * 160 + t;
  float acc = 0.f;
  for (int n = 0; n < 144; n++) acc += bf2f(base[(size_t)n * 160]);
  atomicAdd(&g_ssum[b * 160 + t], 0.1f * acc);
}

// ---------------- squash of class capsules ----------------
__global__ void squash_v_k(int slot, float* __restrict__ clf, int write_clf) {
  int b = blockIdx.x;
  int c = threadIdx.x;
  if (c >= 10) return;
  const float* s = g_ssum + slot * 40960 + b * 160 + c * 16;
  float sq = 0.f;
#pragma unroll
  for (int d = 0; d < 16; d++) sq = fmaf(s[d], s[d], sq);
  float scale = (sq / (1.f + sq)) * rsqrtf(sq + 1e-7f);
  float* vo = g_v + slot * 40960 + b * 160 + c * 16;
#pragma unroll
  for (int d = 0; d < 16; d++) vo[d] = s[d] * scale;
  if (write_clf) clf[b * 10 + c] = scale * sqrtf(sq);
}

// ---------------- routing iteration (bf16 WU input) ----------------
template <int IT>
__global__ __launch_bounds__(256) void routing_iter_k() {
  int b = blockIdx.x;
  int nb = blockIdx.y;
  int t = threadIdx.x;
  int lane = t & 15;
  int grp = t >> 4;

  const float* v0 = g_v;
  const float* v1 = g_v + 40960;
  float* ssum_out = g_ssum + IT * 40960;

  float v0r[10], v1r[10];
#pragma unroll
  for (int c = 0; c < 10; c++) v0r[c] = v0[b * 160 + c * 16 + lane];
  if (IT == 2) {
#pragma unroll
    for (int c = 0; c < 10; c++) v1r[c] = v1[b * 160 + c * 16 + lane];
  }

  float acc[10];
#pragma unroll
  for (int c = 0; c < 10; c++) acc[c] = 0.f;

  for (int ni = 0; ni < 9; ni++) {
    int n = nb * 144 + grp * 9 + ni;
    const u16* row = g_WU + ((size_t)b * 1152 + n) * 160;
    float wu[10];
#pragma unroll
    for (int c = 0; c < 10; c++) wu[c] = bf2f(row[c * 16 + lane]);

    float bij[10];
#pragma unroll
    for (int c = 0; c < 10; c++) {
      float x = v0r[c] * wu[c];
      x += __shfl_xor(x, 1);
      x += __shfl_xor(x, 2);
      x += __shfl_xor(x, 4);
      x += __shfl_xor(x, 8);
      bij[c] = 0.1f * x;
    }

    if (IT == 2) {
      float mx = bij[0];
#pragma unroll
      for (int c = 1; c < 10; c++) mx = fmaxf(mx, bij[c]);
      float e[10], ssum = 0.f;
#pragma unroll
      for (int c = 0; c < 10; c++) {
        e[c] = __expf(bij[c] - mx);
        ssum += e[c];
      }
      float inv = 1.f / ssum;
#pragma unroll
      for (int c = 0; c < 10; c++) {
        float x = v1r[c] * wu[c];
        x += __shfl_xor(x, 1);
        x += __shfl_xor(x, 2);
        x += __shfl_xor(x, 4);
        x += __shfl_xor(x, 8);
        bij[c] = bij[c] + (e[c] * inv) * x;
      }
    }

    float mx = bij[0];
#pragma unroll
    for (int c = 1; c < 10; c++) mx = fmaxf(mx, bij[c]);
    float e[10], ssum = 0.f;
#pragma unroll
    for (int c = 0; c < 10; c++) {
      e[c] = __expf(bij[c] - mx);
      ssum += e[c];
    }
    float inv = 1.f / ssum;
#pragma unroll
    for (int c = 0; c < 10; c++) acc[c] = fmaf(e[c] * inv, wu[c], acc[c]);
  }
#pragma unroll
  for (int c = 0; c < 10; c++)
    atomicAdd(&ssum_out[b * 160 + c * 16 + lane], acc[c]);
}

// ---------------- decoder ----------------
__global__ __launch_bounds__(256) void dec1_k(const int* __restrict__ labels,
                                              const float* __restrict__ w1,
                                              const float* __restrict__ b1) {
  int b = blockIdx.y;
  int j = blockIdx.x * 256 + threadIdx.x;
  int lab = labels[b];
  const float* vv = g_v + 2 * 40960 + b * 160 + lab * 16;
  float acc = b1[j];
#pragma unroll
  for (int d = 0; d < 16; d++)
    acc = fmaf(vv[d], w1[(size_t)(lab * 16 + d) * 512 + j], acc);
  g_h1[b * 512 + j] = fmaxf(acc, 0.f);
}

// dec2: 2 batches per block — w2 stream reused 2x. Grid (4, 128).
__global__ __launch_bounds__(256) void dec2_k(const float* __restrict__ w2,
                                              const float* __restrict__ b2) {
  __shared__ float h_s[2][512];
  int b0 = blockIdx.y * 2;
  int j = blockIdx.x * 256 + threadIdx.x;
  int t = threadIdx.x;
  for (int i = t; i < 1024; i += 256) h_s[i >> 9][i & 511] = g_h1[b0 * 512 + i];
  __syncthreads();
  float a0 = b2[j], a1 = a0;
#pragma unroll 8
  for (int k = 0; k < 512; k++) {
    float wv = w2[(size_t)k * 1024 + j];
    a0 = fmaf(h_s[0][k], wv, a0);
    a1 = fmaf(h_s[1][k], wv, a1);
  }
  g_h2[b0 * 1024 + j] = fmaxf(a0, 0.f);
  g_h2[(b0 + 1) * 1024 + j] = fmaxf(a1, 0.f);
}

// dec3: 2 batches per block — w3 stream reused 2x. Grid (4, 128).
__global__ __launch_bounds__(256) void dec3_k(const float* __restrict__ w3,
                                              const float* __restrict__ b3,
                                              float* __restrict__ out) {
  __shared__ float h_s[2][1024];
  int b0 = blockIdx.y * 2;
  int t = threadIdx.x;
  for (int i = t; i < 2048; i += 256) h_s[i >> 10][i & 1023] = g_h2[b0 * 1024 + i];
  __syncthreads();
  if (t >= 196) return;
  int j = blockIdx.x * 196 + t;
  float a0 = b3[j], a1 = a0;
#pragma unroll 8
  for (int k = 0; k < 1024; k++) {
    float wv = w3[(size_t)k * 784 + j];
    a0 = fmaf(h_s[0][k], wv, a0);
    a1 = fmaf(h_s[1][k], wv, a1);
  }
  out[2560 + b0 * 784 + j] = 1.f / (1.f + __expf(-a0));
  out[2560 + (b0 + 1) * 784 + j] = 1.f / (1.f + __expf(-a1));
}

// ---------------------------------------------------------------------------
extern "C" void kernel_launch(void* const* d_in, const int* in_sizes, int n_in,
                              void* d_out, int out_size, void* d_ws,
                              size_t ws_size, hipStream_t stream) {
  const float* inputs = (const float*)d_in[0];
  const int* labels = (const int*)d_in[1];
  const float* conv1_w = (const float*)d_in[2];
  const float* conv1_b = (const float*)d_in[3];
  const float* pc_w = (const float*)d_in[4];
  const float* pc_b = (const float*)d_in[5];
  const float* rw = (const float*)d_in[6];
  const float* dw1 = (const float*)d_in[7];
  const float* db1 = (const float*)d_in[8];
  const float* dw2 = (const float*)d_in[9];
  const float* db2 = (const float*)d_in[10];
  const float* dw3 = (const float*)d_in[11];
  const float* db3 = (const float*)d_in[12];
  float* out = (float*)d_out;
  (void)d_ws; (void)ws_size; (void)in_sizes; (void)n_in;

  zero_ssum_k<<<(3 * 256 * 160 + 255) / 256, 256, 0, stream>>>();
  wconv_k<<<dim3(16, 32), 256, 0, stream>>>(pc_w);
  wb1_k<<<96, 256, 0, stream>>>(conv1_w);
  im2col_k<<<dim3(256, 2), 256, 0, stream>>>(inputs);
  conv1_mfma_k<<<1600, 256, 0, stream>>>(conv1_b);
  pc_mfma_k<<<dim3(144, KSPLIT), 256, 0, stream>>>();
  squash_u_k<<<9216, 256, 0, stream>>>(pc_b);
  wu_k<<<dim3(1152, 8), 256, 0, stream>>>(rw);
  red0_k<<<dim3(256, 8), 256, 0, stream>>>();
  squash_v_k<<<256, 64, 0, stream>>>(0, nullptr, 0);
  routing_iter_k<1><<<dim3(256, 8), 256, 0, stream>>>();
  squash_v_k<<<256, 64, 0, stream>>>(1, nullptr, 0);
  routing_iter_k<2><<<dim3(256, 8), 256, 0, stream>>>();
  squash_v_k<<<256, 64, 0, stream>>>(2, out, 1);
  dec1_k<<<dim3(2, 256), 256, 0, stream>>>(labels, dw1, db1);
  dec2_k<<<dim3(4, 128), 256, 0, stream>>>(dw2, db2);
  dec3_k<<<dim3(4, 128), 256, 0, stream>>>(dw3, db3, out);
}